// Round 11
// baseline (187.536 us; speedup 1.0000x reference)
//
#include <hip/hip_runtime.h>
#include <hip/hip_bf16.h>
#include <stdint.h>

#define DIMF   1024
#define HEADS  16
#define HD     64
#define BB     2
#define NN     2048
#define NKP    2112   // 2049 keys padded to 33*64
#define NTILE  33

typedef __attribute__((ext_vector_type(8))) __bf16 bf16x8;
typedef __attribute__((ext_vector_type(4))) float  f32x4;

__device__ __forceinline__ float b2f(uint16_t h) {
  union { uint32_t u; float f; } v; v.u = ((uint32_t)h) << 16; return v.f;
}
__device__ __forceinline__ uint16_t f2b(float f) {
  union { float f; uint32_t u; } v; v.f = f;
  uint32_t r = v.u + 0x7FFFu + ((v.u >> 16) & 1u);
  return (uint16_t)(r >> 16);
}
// packed f32x2 -> bf16x2 via the COMPILER intrinsic (round-8 HW-verified order)
__device__ __forceinline__ uint32_t pack2(float a, float b) {
  __hip_bfloat162 h = __float22bfloat162_rn(float2{a, b});
  union { __hip_bfloat162 h; uint32_t u; } v; v.h = h; return v.u;
}

// async global->LDS DMA, 16B per lane. LDS dest = wave-uniform base + lane*16.
__device__ __forceinline__ void gl_lds16(const void* g, void* l) {
  __builtin_amdgcn_global_load_lds(
      (const __attribute__((address_space(1))) void*)g,
      (__attribute__((address_space(3))) void*)l, 16, 0, 0);
}

// ---------------- fp32 -> bf16 bulk convert (float4 loads) ----------------
__global__ __launch_bounds__(256) void cvt_f32_bf16(const float* __restrict__ src,
                                                    uint16_t* __restrict__ dst, int n4) {
  int i = blockIdx.x * 256 + threadIdx.x;
  if (i < n4) {
    float4 v = *(const float4*)&src[i * 4];
    uint16_t* d = dst + i * 4;
    d[0] = f2b(v.x); d[1] = f2b(v.y); d[2] = f2b(v.z); d[3] = f2b(v.w);
  }
}

// -------- transpose + convert (fp32 M x N -> bf16 N x M), 32x32 tiles --------
__global__ __launch_bounds__(256) void transpose_k(const float* __restrict__ src,
                                                   uint16_t* __restrict__ dst, int M, int N) {
  __shared__ uint16_t tile[32][33];
  int bx = blockIdx.x * 32, by = blockIdx.y * 32;
  int x = threadIdx.x, y0 = threadIdx.y;
#pragma unroll
  for (int i = 0; i < 32; i += 8)
    tile[y0 + i][x] = f2b(src[(size_t)(by + y0 + i) * N + bx + x]);
  __syncthreads();
#pragma unroll
  for (int i = 0; i < 32; i += 8)
    dst[(size_t)(bx + y0 + i) * M + by + x] = tile[x][y0 + i];
}

// ---------------- fill void K/V rows + zero padding ----------------
__global__ __launch_bounds__(256) void fill_void(const float* __restrict__ vk,
                                                 const float* __restrict__ vv,
                                                 uint16_t* __restrict__ k_ws,
                                                 uint16_t* __restrict__ vt_ws) {
  int idx = blockIdx.x * 256 + threadIdx.x;   // 0 .. 131071 = BB*HEADS*64*64
  int dd = idx & 63;
  int r  = (idx >> 6) & 63;      // padded key row 2048+r
  int bh = idx >> 12;            // 0..31
  int h  = bh & (HEADS - 1);
  uint16_t kv  = (r == 0) ? f2b(vk[h * HD + dd]) : (uint16_t)0;
  uint16_t vvv = (r == 0) ? f2b(vv[h * HD + dd]) : (uint16_t)0;
  k_ws[((size_t)bh * NKP + NN + r) * HD + dd]  = kv;
  vt_ws[((size_t)bh * HD + dd) * NKP + NN + r] = vvv;
}

// ---------------- GEMM: C[M,N] = A[M,K] * Bt[N,K]^T, bf16 in, fp32 acc ----------------
// EPI 0: scatter bf16 to Q [bh,2048,64] (PRE-SCALED by per-head scale*log2e),
//        K [bh,2112,64], Vt [bh,64,2112]
// EPI 1: add fp32 bias, write FP32 row-major [M,Nout] (d_out is float*)
template<int EPI>
__global__ __launch_bounds__(256) void gemm_bt(const uint16_t* __restrict__ A,
                                               const uint16_t* __restrict__ Bt,
                                               int K, int Nout,
                                               uint16_t* __restrict__ o0,
                                               uint16_t* __restrict__ o1,
                                               uint16_t* __restrict__ o2,
                                               float* __restrict__ fo,
                                               const float* __restrict__ bias,
                                               const float* __restrict__ trace,
                                               const float* __restrict__ factor) {
  __shared__ uint16_t lds_a[128][32];   // linear: required by global_load_lds
  __shared__ uint16_t lds_b[128][32];
  const int m0 = blockIdx.y * 128, n0 = blockIdx.x * 128;
  const int tid = threadIdx.x, lane = tid & 63, wid = tid >> 6;
  const int wm = (wid >> 1) * 64, wn = (wid & 1) * 64;
  const int lr = lane & 15, lg = lane >> 4;
  f32x4 acc[4][4] = {};
  for (int k0 = 0; k0 < K; k0 += 32) {
    __syncthreads();
#pragma unroll
    for (int it = 0; it < 2; ++it) {
      const int chunk = wid * 2 + it;            // 0..7 (1 KiB each)
      const int o = chunk * 1024 + lane * 16;
      const int r = o >> 6, cb = o & 63;
      gl_lds16((const char*)&A[(size_t)(m0 + r) * K + k0] + cb,
               (char*)&lds_a[0][0] + chunk * 1024);
      gl_lds16((const char*)&Bt[(size_t)(n0 + r) * K + k0] + cb,
               (char*)&lds_b[0][0] + chunk * 1024);
    }
    __syncthreads();
    bf16x8 af[4], bf[4];
#pragma unroll
    for (int i = 0; i < 4; ++i)
      af[i] = *(const bf16x8*)((const char*)&lds_a[0][0] + (wm + i * 16 + lr) * 64 + lg * 16);
#pragma unroll
    for (int j = 0; j < 4; ++j)
      bf[j] = *(const bf16x8*)((const char*)&lds_b[0][0] + (wn + j * 16 + lr) * 64 + lg * 16);
#pragma unroll
    for (int i = 0; i < 4; ++i)
#pragma unroll
      for (int j = 0; j < 4; ++j)
        acc[i][j] = __builtin_amdgcn_mfma_f32_16x16x32_bf16(af[i], bf[j], acc[i][j], 0, 0, 0);
  }
#pragma unroll
  for (int i = 0; i < 4; ++i)
#pragma unroll
    for (int j = 0; j < 4; ++j)
#pragma unroll
      for (int r = 0; r < 4; ++r) {
        int mg = m0 + wm + i * 16 + lg * 4 + r;   // C row = m (m89 layout)
        int ng = n0 + wn + j * 16 + lr;            // C col = n
        float v = acc[i][j][r];
        if (EPI == 0) {
          int b = mg >> 11, n = mg & (NN - 1);
          int which = ng >> 10, rem = ng & (DIMF - 1), h = rem >> 6, dd = rem & 63;
          int bh = b * HEADS + h;
          float vv = v;
          if (which == 0) {   // Q: fold (dim^-0.5 / temp) * log2(e) into Q
            float tmp = fmaxf(1.0f + fabsf(trace[h]) * factor[h], 1.0f);
            vv = v * (0.04508422f / tmp);          // 0.03125 * 1.44269504
          }
          uint16_t bv = f2b(vv);
          if (which == 0)      o0[((size_t)bh * NN + n) * HD + dd] = bv;
          else if (which == 1) o1[((size_t)bh * NKP + n) * HD + dd] = bv;
          else                 o2[((size_t)bh * HD + dd) * NKP + n] = bv;  // V transposed
        } else {
          fo[(size_t)mg * Nout + ng] = v + bias[ng];   // FP32 output
        }
      }
}

// ---- flash attention: round-10 math + K/V DOUBLE-BUFFER stage-ahead + L2 grid ----
// 4 waves x 16 q-rows. Per tile: issue DMA for t+1 into buf^1, compute tile t from
// buf, THEN one __syncthreads (drains vmcnt; the t+1 loads had the whole compute
// phase to land -> no serial stage->drain->compute chain). Grid: bh fastest ->
// XCD = bh%8 serves 4 bh = 2.2 MB K/V, L2-resident (round-9-proven: FETCH 71->13MB).
// Swapped QK^T (S^T = mfma(K,Q)), in-register pack2 P, PV = mfma(P, V^T), all
// round-8/10-proven. Q pre-scaled by scale*log2e -> p = exp2f(s); phantom keys
// give p=1, subtracted at the end.
__global__ __launch_bounds__(256) void attn_k(const uint16_t* __restrict__ q_ws,
                                              const uint16_t* __restrict__ k_ws,
                                              const uint16_t* __restrict__ vt_ws,
                                              uint16_t* __restrict__ o_ws) {
  __shared__ uint16_t ldsk[2][64][64];   // [buf][key][d], swizzled cols (16 KB)
  __shared__ uint16_t ldsv[2][64][64];   // [buf][d][key], swizzled cols (16 KB)
  __shared__ uint16_t ldsp[4][16][72];   // [wave][q][key(+pad)]        (9.2 KB)
  const int bh = blockIdx.x;             // FASTEST dim -> XCD = bh%8 (L2 locality)
  const int qb = blockIdx.y;
  const int h = bh & (HEADS - 1), b = bh >> 4;
  const int tid = threadIdx.x, lane = tid & 63, wid = tid >> 6;
  const int lr = lane & 15, lg = lane >> 4;

  const int qrow0 = qb * 64 + wid * 16;
  const uint16_t* qp = q_ws + ((size_t)bh * NN + qrow0 + lr) * HD;
  bf16x8 qf[2];
  qf[0] = *(const bf16x8*)(qp + lg * 8);
  qf[1] = *(const bf16x8*)(qp + 32 + lg * 8);

  f32x4 acc[4] = {};
  float lsum = 0.f;

#define STAGE(buf, t)                                                              \
  {                                                                                \
    const int t0_ = (t) * 64;                                                      \
    _Pragma("unroll")                                                              \
    for (int it = 0; it < 2; ++it) {                                               \
      const int chunk = wid * 2 + it;            /* 0..7 (1 KiB each) */           \
      const int o = chunk * 1024 + lane * 16;                                      \
      const int r = o >> 7, cb = o & 127;        /* 128 B per row */               \
      const int scb = cb ^ ((r & 7) << 4);       /* pre-swizzled source col */     \
      gl_lds16((const char*)&k_ws[((size_t)bh * NKP + t0_ + r) * HD] + scb,        \
               (char*)&ldsk[buf][0][0] + chunk * 1024);                            \
      gl_lds16((const char*)&vt_ws[((size_t)bh * HD + r) * NKP + t0_] + scb,       \
               (char*)&ldsv[buf][0][0] + chunk * 1024);                            \
    }                                                                              \
  }

  STAGE(0, 0);
  __syncthreads();   // vmcnt(0) drained: tile 0 visible
  int cur = 0;

  for (int t = 0; t < NTILE; ++t) {
    const int tn = (t + 1 < NTILE) ? t + 1 : t;  // last iter: harmless restage
    STAGE(cur ^ 1, tn);                          // issue BEFORE compute (T3-lite)

    // S^T = K Q^T per 16-key chunk; p = exp2(s); pack pairs; stage ldsp[q][key]
#pragma unroll
    for (int c = 0; c < 4; ++c) {
      const int row = c * 16 + lr;
      const int rsw = (row & 7) << 4;
      bf16x8 kf0 = *(const bf16x8*)((const char*)&ldsk[cur][0][0] + row * 128 + ((lg * 16) ^ rsw));
      bf16x8 kf1 = *(const bf16x8*)((const char*)&ldsk[cur][0][0] + row * 128 + ((64 + lg * 16) ^ rsw));
      f32x4 s = {};
      s = __builtin_amdgcn_mfma_f32_16x16x32_bf16(kf0, qf[0], s, 0, 0, 0);
      s = __builtin_amdgcn_mfma_f32_16x16x32_bf16(kf1, qf[1], s, 0, 0, 0);
      float p0 = exp2f(s[0]), p1 = exp2f(s[1]);
      float p2 = exp2f(s[2]), p3 = exp2f(s[3]);
      lsum += (p0 + p1) + (p2 + p3);
      *(uint32_t*)&ldsp[wid][lr][c * 16 + lg * 4]     = pack2(p0, p1);
      *(uint32_t*)&ldsp[wid][lr][c * 16 + lg * 4 + 2] = pack2(p2, p3);
    }
    // ordering fence: u32 LDS writes -> bf16x8 LDS reads, same wave, no barrier
    asm volatile("" ::: "memory");
    __builtin_amdgcn_sched_barrier(0);

    // O += P V : A = P[q rows][k], B = V^T[key][d] (proven pattern)
#pragma unroll
    for (int kk = 0; kk < 2; ++kk) {
      bf16x8 pf = *(const bf16x8*)&ldsp[wid][lr][kk * 32 + lg * 8];
#pragma unroll
      for (int cd = 0; cd < 4; ++cd) {
        const int row = cd * 16 + lr;
        const int cbb = (kk * 64 + lg * 16) ^ ((row & 7) << 4);
        bf16x8 vf = *(const bf16x8*)((const char*)&ldsv[cur][0][0] + row * 128 + cbb);
        acc[cd] = __builtin_amdgcn_mfma_f32_16x16x32_bf16(pf, vf, acc[cd], 0, 0, 0);
      }
    }
    __syncthreads();   // next tile landed (had full compute to arrive); ldsp WAR safe
    cur ^= 1;
  }

  // l for q=lr (partial over lg's key groups): reduce over lg; route via shfl
  lsum += __shfl_xor(lsum, 16); lsum += __shfl_xor(lsum, 32);

#pragma unroll
  for (int r = 0; r < 4; ++r) {
    const int src = lg * 4 + r;                    // lane holding l for this out row
    const float inv = 1.0f / (__shfl(lsum, src) - 63.0f);
    const int na = qrow0 + lg * 4 + r;             // O row q = lg*4+r
    size_t base = ((size_t)b * NN + na) * DIMF + h * HD;
#pragma unroll
    for (int cd = 0; cd < 4; ++cd)
      o_ws[base + cd * 16 + lr] = f2b(acc[cd][r] * inv);
  }
}

extern "C" void kernel_launch(void* const* d_in, const int* in_sizes, int n_in,
                              void* d_out, int out_size, void* d_ws, size_t ws_size,
                              hipStream_t stream) {
  const float* x      = (const float*)d_in[0];
  const float* wqkv   = (const float*)d_in[1];
  const float* wout   = (const float*)d_in[2];
  const float* bout   = (const float*)d_in[3];
  // d_in[4] = void_q: unused (void query row is dropped by the reference)
  const float* voidk  = (const float*)d_in[5];
  const float* voidv  = (const float*)d_in[6];
  const float* trace  = (const float*)d_in[7];
  const float* factor = (const float*)d_in[8];
  float* out = (float*)d_out;           // reference output dtype is FP32

  uint16_t* ws    = (uint16_t*)d_ws;
  uint16_t* x_bf  = ws;                       // 2*2048*1024  = 4,194,304 elems
  uint16_t* o_ws  = x_bf;                     // ALIAS: x_bf dead after gemm<0>
  uint16_t* wqkvT = x_bf  + 4194304;          // 3072*1024    = 3,145,728
  uint16_t* woutT = wqkvT + 3145728;          // 1024*1024    = 1,048,576
  uint16_t* q_ws  = woutT + 1048576;          // 2*16*2048*64 = 4,194,304
  uint16_t* k_ws  = q_ws  + 4194304;          // 2*16*2112*64 = 4,325,376
  uint16_t* vt_ws = k_ws  + 4325376;          // 4,325,376   (total ~42.5 MB)

  cvt_f32_bf16<<<dim3(4194304 / 4 / 256), dim3(256), 0, stream>>>(x, x_bf, 4194304 / 4);
  transpose_k<<<dim3(3072 / 32, 1024 / 32), dim3(32, 8), 0, stream>>>(wqkv, wqkvT, 1024, 3072);
  transpose_k<<<dim3(1024 / 32, 1024 / 32), dim3(32, 8), 0, stream>>>(wout, woutT, 1024, 1024);
  fill_void<<<dim3(512), dim3(256), 0, stream>>>(voidk, voidv, k_ws, vt_ws);
  gemm_bt<0><<<dim3(3072 / 128, 4096 / 128), dim3(256), 0, stream>>>(
      x_bf, wqkvT, 1024, 3072, q_ws, k_ws, vt_ws, nullptr, nullptr, trace, factor);
  attn_k<<<dim3(HEADS * BB, NN / 64), dim3(256), 0, stream>>>(q_ws, k_ws, vt_ws, o_ws);
  gemm_bt<1><<<dim3(1024 / 128, 4096 / 128), dim3(256), 0, stream>>>(
      o_ws, woutT, 1024, 1024, nullptr, nullptr, nullptr, out, bout, nullptr, nullptr);
}

// Round 12
// 161.155 us; speedup vs baseline: 1.1637x; 1.1637x over previous
//
#include <hip/hip_runtime.h>
#include <stdint.h>

#define DIMF   1024
#define HEADS  16
#define HD     64
#define BB     2
#define NN     2048
#define NKP    2112   // 2049 keys padded to 33*64
#define NTILE  33

typedef __attribute__((ext_vector_type(8))) __bf16 bf16x8;
typedef __attribute__((ext_vector_type(4))) float  f32x4;

__device__ __forceinline__ float b2f(uint16_t h) {
  union { uint32_t u; float f; } v; v.u = ((uint32_t)h) << 16; return v.f;
}
__device__ __forceinline__ uint16_t f2b(float f) {
  union { float f; uint32_t u; } v; v.f = f;
  uint32_t r = v.u + 0x7FFFu + ((v.u >> 16) & 1u);
  return (uint16_t)(r >> 16);
}

// async global->LDS DMA, 16B per lane. LDS dest = wave-uniform base + lane*16.
__device__ __forceinline__ void gl_lds16(const void* g, void* l) {
  __builtin_amdgcn_global_load_lds(
      (const __attribute__((address_space(1))) void*)g,
      (__attribute__((address_space(3))) void*)l, 16, 0, 0);
}

// ---------------- fp32 -> bf16 bulk convert (float4 loads) ----------------
__global__ __launch_bounds__(256) void cvt_f32_bf16(const float* __restrict__ src,
                                                    uint16_t* __restrict__ dst, int n4) {
  int i = blockIdx.x * 256 + threadIdx.x;
  if (i < n4) {
    float4 v = *(const float4*)&src[i * 4];
    uint16_t* d = dst + i * 4;
    d[0] = f2b(v.x); d[1] = f2b(v.y); d[2] = f2b(v.z); d[3] = f2b(v.w);
  }
}

// -------- transpose + convert (fp32 M x N -> bf16 N x M), 32x32 tiles --------
__global__ __launch_bounds__(256) void transpose_k(const float* __restrict__ src,
                                                   uint16_t* __restrict__ dst, int M, int N) {
  __shared__ uint16_t tile[32][33];
  int bx = blockIdx.x * 32, by = blockIdx.y * 32;
  int x = threadIdx.x, y0 = threadIdx.y;
#pragma unroll
  for (int i = 0; i < 32; i += 8)
    tile[y0 + i][x] = f2b(src[(size_t)(by + y0 + i) * N + bx + x]);
  __syncthreads();
#pragma unroll
  for (int i = 0; i < 32; i += 8)
    dst[(size_t)(bx + y0 + i) * M + by + x] = tile[x][y0 + i];
}

// ---------------- fill void K/V rows + zero padding ----------------
__global__ __launch_bounds__(256) void fill_void(const float* __restrict__ vk,
                                                 const float* __restrict__ vv,
                                                 uint16_t* __restrict__ k_ws,
                                                 uint16_t* __restrict__ vt_ws) {
  int idx = blockIdx.x * 256 + threadIdx.x;   // 0 .. 131071 = BB*HEADS*64*64
  int dd = idx & 63;
  int r  = (idx >> 6) & 63;      // padded key row 2048+r
  int bh = idx >> 12;            // 0..31
  int h  = bh & (HEADS - 1);
  uint16_t kv  = (r == 0) ? f2b(vk[h * HD + dd]) : (uint16_t)0;
  uint16_t vvv = (r == 0) ? f2b(vv[h * HD + dd]) : (uint16_t)0;
  k_ws[((size_t)bh * NKP + NN + r) * HD + dd]  = kv;
  vt_ws[((size_t)bh * HD + dd) * NKP + NN + r] = vvv;
}

// ---------------- GEMM: C[M,N] = A[M,K] * Bt[N,K]^T, bf16 in, fp32 acc ----------------
// m97 structure: BK=32, linear LDS [128][32], global_load_lds dwordx4 staging.
// EPI 0: scatter bf16 to Q [bh,2048,64], K [bh,2112,64], Vt [bh,64,2112]
// EPI 1: add fp32 bias, write FP32 row-major [M,Nout]
template<int EPI>
__global__ __launch_bounds__(256) void gemm_bt(const uint16_t* __restrict__ A,
                                               const uint16_t* __restrict__ Bt,
                                               int K, int Nout,
                                               uint16_t* __restrict__ o0,
                                               uint16_t* __restrict__ o1,
                                               uint16_t* __restrict__ o2,
                                               float* __restrict__ fo,
                                               const float* __restrict__ bias) {
  __shared__ uint16_t lds_a[128][32];   // linear: required by global_load_lds
  __shared__ uint16_t lds_b[128][32];
  const int m0 = blockIdx.y * 128, n0 = blockIdx.x * 128;
  const int tid = threadIdx.x, lane = tid & 63, wid = tid >> 6;
  const int wm = (wid >> 1) * 64, wn = (wid & 1) * 64;
  const int lr = lane & 15, lg = lane >> 4;
  f32x4 acc[4][4] = {};
  for (int k0 = 0; k0 < K; k0 += 32) {
    __syncthreads();
#pragma unroll
    for (int it = 0; it < 2; ++it) {
      const int chunk = wid * 2 + it;            // 0..7 (1 KiB each)
      const int o = chunk * 1024 + lane * 16;
      const int r = o >> 6, cb = o & 63;
      gl_lds16((const char*)&A[(size_t)(m0 + r) * K + k0] + cb,
               (char*)&lds_a[0][0] + chunk * 1024);
      gl_lds16((const char*)&Bt[(size_t)(n0 + r) * K + k0] + cb,
               (char*)&lds_b[0][0] + chunk * 1024);
    }
    __syncthreads();
    bf16x8 af[4], bf[4];
#pragma unroll
    for (int i = 0; i < 4; ++i)
      af[i] = *(const bf16x8*)((const char*)&lds_a[0][0] + (wm + i * 16 + lr) * 64 + lg * 16);
#pragma unroll
    for (int j = 0; j < 4; ++j)
      bf[j] = *(const bf16x8*)((const char*)&lds_b[0][0] + (wn + j * 16 + lr) * 64 + lg * 16);
#pragma unroll
    for (int i = 0; i < 4; ++i)
#pragma unroll
      for (int j = 0; j < 4; ++j)
        acc[i][j] = __builtin_amdgcn_mfma_f32_16x16x32_bf16(af[i], bf[j], acc[i][j], 0, 0, 0);
  }
#pragma unroll
  for (int i = 0; i < 4; ++i)
#pragma unroll
    for (int j = 0; j < 4; ++j)
#pragma unroll
      for (int r = 0; r < 4; ++r) {
        int mg = m0 + wm + i * 16 + lg * 4 + r;   // C row = m (m89 layout)
        int ng = n0 + wn + j * 16 + lr;            // C col = n
        float v = acc[i][j][r];
        if (EPI == 0) {
          int b = mg >> 11, n = mg & (NN - 1);
          int which = ng >> 10, rem = ng & (DIMF - 1), h = rem >> 6, dd = rem & 63;
          int bh = b * HEADS + h;
          uint16_t bv = f2b(v);
          if (which == 0)      o0[((size_t)bh * NN + n) * HD + dd] = bv;
          else if (which == 1) o1[((size_t)bh * NKP + n) * HD + dd] = bv;
          else                 o2[((size_t)bh * HD + dd) * NKP + n] = bv;  // V transposed
        } else {
          fo[(size_t)mg * Nout + ng] = v + bias[ng];   // FP32 output
        }
      }
}

// -------- flash attention: EXACT round-6 kernel, only the grid mapping changed --------
// 4 waves x 16 q-rows, single-buffered K/V via global_load_lds, XOR-swizzled reads.
// Grid: bh FASTEST -> block%8 = bh%8 pins each bh to one XCD; 4 bh x 540 KB = 2.2 MB
// K/V resident in that XCD's L2 -> per-tile vmcnt drain waits on L2 hits (~200-400 cyc)
// instead of HBM misses (~900 cyc). (Round-9/11-proven: FETCH 71.7 -> ~13 MB.)
// Fixed-max softmax: |logit| <= ~2; zero-padded phantom keys give p=1, minus 63 at end.
__global__ __launch_bounds__(256) void attn_k(const uint16_t* __restrict__ q_ws,
                                              const uint16_t* __restrict__ k_ws,
                                              const uint16_t* __restrict__ vt_ws,
                                              const float* __restrict__ trace,
                                              const float* __restrict__ factor,
                                              uint16_t* __restrict__ o_ws) {
  __shared__ uint16_t ldsk[64][64];      // [key][d]   128 B rows, swizzled cols
  __shared__ uint16_t ldsv[64][64];      // [d][key]   (from Vt), swizzled cols
  __shared__ uint16_t ldsp[4][16][72];   // per-wave P re-layout buffer (+pad)
  const int bh = blockIdx.x;             // FASTEST dim -> XCD = bh%8 (L2 locality)
  const int qb = blockIdx.y;
  const int h = bh & (HEADS - 1), b = bh >> 4;
  const int tid = threadIdx.x, lane = tid & 63, wid = tid >> 6;
  const int lr = lane & 15, lg = lane >> 4;

  const float temp  = fmaxf(1.0f + fabsf(trace[h]) * factor[h], 1.0f);
  const float scale = 0.03125f / temp;   // dim^-0.5 / temperature

  const int qrow0 = qb * 64 + wid * 16;
  const uint16_t* qrow = q_ws + ((size_t)bh * NN + qrow0 + lr) * HD;
  bf16x8 qf[2];
  qf[0] = *(const bf16x8*)(qrow + lg * 8);
  qf[1] = *(const bf16x8*)(qrow + 32 + lg * 8);

  f32x4 acc[4] = {};
  float lsum[4] = {0.f, 0.f, 0.f, 0.f};

  for (int t = 0; t < NTILE; ++t) {
    const int t0 = t * 64;
    __syncthreads();
#pragma unroll
    for (int it = 0; it < 2; ++it) {
      const int chunk = wid * 2 + it;           // 0..7 (1 KiB each)
      const int o = chunk * 1024 + lane * 16;
      const int r = o >> 7, cb = o & 127;       // 128 B per row
      const int scb = cb ^ ((r & 7) << 4);      // pre-swizzled source col
      gl_lds16((const char*)&k_ws[((size_t)bh * NKP + t0 + r) * HD] + scb,
               (char*)&ldsk[0][0] + chunk * 1024);
      gl_lds16((const char*)&vt_ws[((size_t)bh * HD + r) * NKP + t0] + scb,
               (char*)&ldsv[0][0] + chunk * 1024);
    }
    __syncthreads();

    // S = Q K^T (4 chunks of 16 keys), swizzled kf reads
    f32x4 s[4];
#pragma unroll
    for (int c = 0; c < 4; ++c) {
      f32x4 sa = {};
#pragma unroll
      for (int kk = 0; kk < 2; ++kk) {
        const int row = c * 16 + lr;
        const int cbb = (kk * 64 + lg * 16) ^ ((row & 7) << 4);
        bf16x8 kf = *(const bf16x8*)((const char*)&ldsk[0][0] + row * 128 + cbb);
        sa = __builtin_amdgcn_mfma_f32_16x16x32_bf16(qf[kk], kf, sa, 0, 0, 0);
      }
      s[c] = sa;
    }
    // p = exp(s*scale); accumulate per-lane partial l; stage P (C-frag -> A-frag)
#pragma unroll
    for (int c = 0; c < 4; ++c)
#pragma unroll
      for (int r = 0; r < 4; ++r) {
        float p = __expf(s[c][r] * scale);
        lsum[r] += p;
        ldsp[wid][lg * 4 + r][c * 16 + lr] = f2b(p);
      }
    // ordering fence: scalar u16 writes -> vector bf16x8 read, same wave
    asm volatile("" ::: "memory");
    __builtin_amdgcn_sched_barrier(0);
    // O += P V, swizzled vf reads
#pragma unroll
    for (int kk = 0; kk < 2; ++kk) {
      bf16x8 pf = *(const bf16x8*)&ldsp[wid][lr][kk * 32 + lg * 8];
#pragma unroll
      for (int cd = 0; cd < 4; ++cd) {
        const int row = cd * 16 + lr;
        const int cbb = (kk * 64 + lg * 16) ^ ((row & 7) << 4);
        bf16x8 vf = *(const bf16x8*)((const char*)&ldsv[0][0] + row * 128 + cbb);
        acc[cd] = __builtin_amdgcn_mfma_f32_16x16x32_bf16(pf, vf, acc[cd], 0, 0, 0);
      }
    }
  }
  // final l reduce (16-lane groups), drop the 63 phantom keys, normalize, write O
#pragma unroll
  for (int r = 0; r < 4; ++r) {
    float l = lsum[r];
    l += __shfl_xor(l, 1); l += __shfl_xor(l, 2);
    l += __shfl_xor(l, 4); l += __shfl_xor(l, 8);
    l -= 63.0f;
    const float inv = 1.0f / l;
    const int n = qrow0 + lg * 4 + r;
    size_t base = ((size_t)b * NN + n) * DIMF + h * HD;
#pragma unroll
    for (int cd = 0; cd < 4; ++cd)
      o_ws[base + cd * 16 + lr] = f2b(acc[cd][r] * inv);
  }
}

extern "C" void kernel_launch(void* const* d_in, const int* in_sizes, int n_in,
                              void* d_out, int out_size, void* d_ws, size_t ws_size,
                              hipStream_t stream) {
  const float* x      = (const float*)d_in[0];
  const float* wqkv   = (const float*)d_in[1];
  const float* wout   = (const float*)d_in[2];
  const float* bout   = (const float*)d_in[3];
  // d_in[4] = void_q: unused (void query row is dropped by the reference)
  const float* voidk  = (const float*)d_in[5];
  const float* voidv  = (const float*)d_in[6];
  const float* trace  = (const float*)d_in[7];
  const float* factor = (const float*)d_in[8];
  float* out = (float*)d_out;           // reference output dtype is FP32

  uint16_t* ws    = (uint16_t*)d_ws;
  uint16_t* x_bf  = ws;                       // 2*2048*1024  = 4,194,304 elems
  uint16_t* o_ws  = x_bf;                     // ALIAS: x_bf dead after gemm<0>
  uint16_t* wqkvT = x_bf  + 4194304;          // 3072*1024    = 3,145,728
  uint16_t* woutT = wqkvT + 3145728;          // 1024*1024    = 1,048,576
  uint16_t* q_ws  = woutT + 1048576;          // 2*16*2048*64 = 4,194,304
  uint16_t* k_ws  = q_ws  + 4194304;          // 2*16*2112*64 = 4,325,376
  uint16_t* vt_ws = k_ws  + 4325376;          // 4,325,376   (total ~42.5 MB)

  cvt_f32_bf16<<<dim3(4194304 / 4 / 256), dim3(256), 0, stream>>>(x, x_bf, 4194304 / 4);
  transpose_k<<<dim3(3072 / 32, 1024 / 32), dim3(32, 8), 0, stream>>>(wqkv, wqkvT, 1024, 3072);
  transpose_k<<<dim3(1024 / 32, 1024 / 32), dim3(32, 8), 0, stream>>>(wout, woutT, 1024, 1024);
  fill_void<<<dim3(512), dim3(256), 0, stream>>>(voidk, voidv, k_ws, vt_ws);
  gemm_bt<0><<<dim3(3072 / 128, 4096 / 128), dim3(256), 0, stream>>>(
      x_bf, wqkvT, 1024, 3072, q_ws, k_ws, vt_ws, nullptr, nullptr);
  attn_k<<<dim3(HEADS * BB, NN / 64), dim3(256), 0, stream>>>(
      q_ws, k_ws, vt_ws, trace, factor, o_ws);
  gemm_bt<1><<<dim3(1024 / 128, 4096 / 128), dim3(256), 0, stream>>>(
      o_ws, woutT, 1024, 1024, nullptr, nullptr, nullptr, out, bout);
}

// Round 13
// 154.074 us; speedup vs baseline: 1.2172x; 1.0460x over previous
//
#include <hip/hip_runtime.h>
#include <stdint.h>

#define DIMF   1024
#define HEADS  16
#define HD     64
#define BB     2
#define NN     2048
#define NKP    2112   // 2049 keys padded to 33*64
#define NTILE  33

typedef __attribute__((ext_vector_type(8))) __bf16 bf16x8;
typedef __attribute__((ext_vector_type(4))) float  f32x4;

__device__ __forceinline__ float b2f(uint16_t h) {
  union { uint32_t u; float f; } v; v.u = ((uint32_t)h) << 16; return v.f;
}
__device__ __forceinline__ uint16_t f2b(float f) {
  union { float f; uint32_t u; } v; v.f = f;
  uint32_t r = v.u + 0x7FFFu + ((v.u >> 16) & 1u);
  return (uint16_t)(r >> 16);
}

// async global->LDS DMA, 16B per lane. LDS dest = wave-uniform base + lane*16.
__device__ __forceinline__ void gl_lds16(const void* g, void* l) {
  __builtin_amdgcn_global_load_lds(
      (const __attribute__((address_space(1))) void*)g,
      (__attribute__((address_space(3))) void*)l, 16, 0, 0);
}

// ---- merged preprocessing: blocks [0,4096) cvt x->bf16; [4096,4608) void fill ----
__global__ __launch_bounds__(256) void prep_k(const float* __restrict__ x,
                                              uint16_t* __restrict__ x_bf,
                                              const float* __restrict__ vk,
                                              const float* __restrict__ vv,
                                              uint16_t* __restrict__ k_ws,
                                              uint16_t* __restrict__ vt_ws) {
  if (blockIdx.x < 4096) {
    int i = blockIdx.x * 256 + threadIdx.x;      // < 1048576 float4s
    float4 v = *(const float4*)&x[(size_t)i * 4];
    uint16_t* d = x_bf + (size_t)i * 4;
    d[0] = f2b(v.x); d[1] = f2b(v.y); d[2] = f2b(v.z); d[3] = f2b(v.w);
  } else {
    int idx = (blockIdx.x - 4096) * 256 + threadIdx.x;  // 0 .. 131071
    int dd = idx & 63;
    int r  = (idx >> 6) & 63;      // padded key row 2048+r
    int bh = idx >> 12;            // 0..31
    int h  = bh & (HEADS - 1);
    uint16_t kv  = (r == 0) ? f2b(vk[h * HD + dd]) : (uint16_t)0;
    uint16_t vvv = (r == 0) ? f2b(vv[h * HD + dd]) : (uint16_t)0;
    k_ws[((size_t)bh * NKP + NN + r) * HD + dd]  = kv;
    vt_ws[((size_t)bh * HD + dd) * NKP + NN + r] = vvv;
  }
}

// ---- merged transpose+convert (fp32 MxN -> bf16 NxM): z=0 wqkv, z=1 wout ----
__global__ __launch_bounds__(256) void transpose2_k(const float* __restrict__ w1,
                                                    uint16_t* __restrict__ d1,
                                                    const float* __restrict__ w2,
                                                    uint16_t* __restrict__ d2) {
  const int z = blockIdx.z;
  if (z == 1 && blockIdx.x >= 32) return;        // wout: 1024/32 = 32 x-tiles
  const float* src = z ? w2 : w1;
  uint16_t*   dst = z ? d2 : d1;
  const int M = 1024, N = z ? 1024 : 3072;
  __shared__ uint16_t tile[32][33];
  int bx = blockIdx.x * 32, by = blockIdx.y * 32;
  int x = threadIdx.x & 31, y0 = (threadIdx.x >> 5) * 4;   // 8 y-groups of 4
#pragma unroll
  for (int i = 0; i < 4; ++i)
    tile[y0 + i][x] = f2b(src[(size_t)(by + y0 + i) * N + bx + x]);
  __syncthreads();
#pragma unroll
  for (int i = 0; i < 4; ++i)
    dst[(size_t)(bx + y0 + i) * M + by + x] = tile[x][y0 + i];
}

// ---------------- GEMM: C[M,N] = A[M,K] * Bt[N,K]^T, bf16 in, fp32 acc ----------------
// EPI 0: scatter bf16 to Q [bh,2048,64], K [bh,2112,64], Vt [bh,64,2112]
// EPI 1: add fp32 bias, write FP32 row-major [M,Nout]
template<int EPI>
__global__ __launch_bounds__(256) void gemm_bt(const uint16_t* __restrict__ A,
                                               const uint16_t* __restrict__ Bt,
                                               int K, int Nout,
                                               uint16_t* __restrict__ o0,
                                               uint16_t* __restrict__ o1,
                                               uint16_t* __restrict__ o2,
                                               float* __restrict__ fo,
                                               const float* __restrict__ bias) {
  __shared__ uint16_t lds_a[128][32];   // linear: required by global_load_lds
  __shared__ uint16_t lds_b[128][32];
  const int m0 = blockIdx.y * 128, n0 = blockIdx.x * 128;
  const int tid = threadIdx.x, lane = tid & 63, wid = tid >> 6;
  const int wm = (wid >> 1) * 64, wn = (wid & 1) * 64;
  const int lr = lane & 15, lg = lane >> 4;
  f32x4 acc[4][4] = {};
  for (int k0 = 0; k0 < K; k0 += 32) {
    __syncthreads();
#pragma unroll
    for (int it = 0; it < 2; ++it) {
      const int chunk = wid * 2 + it;            // 0..7 (1 KiB each)
      const int o = chunk * 1024 + lane * 16;
      const int r = o >> 6, cb = o & 63;
      gl_lds16((const char*)&A[(size_t)(m0 + r) * K + k0] + cb,
               (char*)&lds_a[0][0] + chunk * 1024);
      gl_lds16((const char*)&Bt[(size_t)(n0 + r) * K + k0] + cb,
               (char*)&lds_b[0][0] + chunk * 1024);
    }
    __syncthreads();
    bf16x8 af[4], bf[4];
#pragma unroll
    for (int i = 0; i < 4; ++i)
      af[i] = *(const bf16x8*)((const char*)&lds_a[0][0] + (wm + i * 16 + lr) * 64 + lg * 16);
#pragma unroll
    for (int j = 0; j < 4; ++j)
      bf[j] = *(const bf16x8*)((const char*)&lds_b[0][0] + (wn + j * 16 + lr) * 64 + lg * 16);
#pragma unroll
    for (int i = 0; i < 4; ++i)
#pragma unroll
      for (int j = 0; j < 4; ++j)
        acc[i][j] = __builtin_amdgcn_mfma_f32_16x16x32_bf16(af[i], bf[j], acc[i][j], 0, 0, 0);
  }
#pragma unroll
  for (int i = 0; i < 4; ++i)
#pragma unroll
    for (int j = 0; j < 4; ++j)
#pragma unroll
      for (int r = 0; r < 4; ++r) {
        int mg = m0 + wm + i * 16 + lg * 4 + r;   // C row = m (m89 layout)
        int ng = n0 + wn + j * 16 + lr;            // C col = n
        float v = acc[i][j][r];
        if (EPI == 0) {
          int b = mg >> 11, n = mg & (NN - 1);
          int which = ng >> 10, rem = ng & (DIMF - 1), h = rem >> 6, dd = rem & 63;
          int bh = b * HEADS + h;
          uint16_t bv = f2b(v);
          if (which == 0)      o0[((size_t)bh * NN + n) * HD + dd] = bv;
          else if (which == 1) o1[((size_t)bh * NKP + n) * HD + dd] = bv;
          else                 o2[((size_t)bh * HD + dd) * NKP + n] = bv;  // V transposed
        } else {
          fo[(size_t)mg * Nout + ng] = v + bias[ng];   // FP32 output
        }
      }
}

// ---- flash attention: round-12 structure frozen; VALU diet + setprio (T5) ----
// 4 waves x 16 q-rows, single-buffered K/V via global_load_lds, XOR-swizzled reads.
// bh-fastest grid (L2: FETCH 71.7->12.6 MB, round-12-proven). P stored TRUNCATED
// to bf16 with l accumulated from the SAME truncated value (ratio-consistent, no
// bias). All LDS read addresses hoisted (loop-invariant; row&7 == lr&7).
__global__ __launch_bounds__(256) void attn_k(const uint16_t* __restrict__ q_ws,
                                              const uint16_t* __restrict__ k_ws,
                                              const uint16_t* __restrict__ vt_ws,
                                              const float* __restrict__ trace,
                                              const float* __restrict__ factor,
                                              uint16_t* __restrict__ o_ws) {
  __shared__ uint16_t ldsk[64][64];      // [key][d]   128 B rows, swizzled cols
  __shared__ uint16_t ldsv[64][64];      // [d][key]   (from Vt), swizzled cols
  __shared__ uint16_t ldsp[4][16][72];   // per-wave P re-layout buffer (+pad)
  const int bh = blockIdx.x;             // FASTEST dim -> XCD = bh%8 (L2 locality)
  const int qb = blockIdx.y;
  const int h = bh & (HEADS - 1), b = bh >> 4;
  const int tid = threadIdx.x, lane = tid & 63, wid = tid >> 6;
  const int lr = lane & 15, lg = lane >> 4;

  const float temp  = fmaxf(1.0f + fabsf(trace[h]) * factor[h], 1.0f);
  const float scale = 0.03125f / temp;   // dim^-0.5 / temperature

  const int qrow0 = qb * 64 + wid * 16;
  const uint16_t* qrow = q_ws + ((size_t)bh * NN + qrow0 + lr) * HD;
  bf16x8 qf[2];
  qf[0] = *(const bf16x8*)(qrow + lg * 8);
  qf[1] = *(const bf16x8*)(qrow + 32 + lg * 8);

  // hoisted loop-invariant LDS read addresses (row = c*16+lr -> row&7 == lr&7)
  const int rsw = (lr & 7) << 4;
  const char* kb0 = (const char*)&ldsk[0][0] + lr * 128 + ((lg * 16) ^ rsw);
  const char* kb1 = (const char*)&ldsk[0][0] + lr * 128 + ((64 + lg * 16) ^ rsw);
  const char* vb0 = (const char*)&ldsv[0][0] + lr * 128 + ((lg * 16) ^ rsw);
  const char* vb1 = (const char*)&ldsv[0][0] + lr * 128 + ((64 + lg * 16) ^ rsw);
  const char* pr  = (const char*)&ldsp[wid][lr][lg * 8];

  f32x4 acc[4] = {};
  float lsum[4] = {0.f, 0.f, 0.f, 0.f};

  for (int t = 0; t < NTILE; ++t) {
    const int t0 = t * 64;
    __syncthreads();
#pragma unroll
    for (int it = 0; it < 2; ++it) {
      const int chunk = wid * 2 + it;           // 0..7 (1 KiB each)
      const int o = chunk * 1024 + lane * 16;
      const int r = o >> 7, cb = o & 127;       // 128 B per row
      const int scb = cb ^ ((r & 7) << 4);      // pre-swizzled source col
      gl_lds16((const char*)&k_ws[((size_t)bh * NKP + t0 + r) * HD] + scb,
               (char*)&ldsk[0][0] + chunk * 1024);
      gl_lds16((const char*)&vt_ws[((size_t)bh * HD + r) * NKP + t0] + scb,
               (char*)&ldsv[0][0] + chunk * 1024);
    }
    __syncthreads();

    // S = Q K^T (4 chunks of 16 keys)
    f32x4 s[4];
#pragma unroll
    for (int c = 0; c < 4; ++c) {
      bf16x8 kf0 = *(const bf16x8*)(kb0 + c * 2048);
      bf16x8 kf1 = *(const bf16x8*)(kb1 + c * 2048);
      f32x4 sa = {};
      __builtin_amdgcn_s_setprio(1);
      sa = __builtin_amdgcn_mfma_f32_16x16x32_bf16(qf[0], kf0, sa, 0, 0, 0);
      sa = __builtin_amdgcn_mfma_f32_16x16x32_bf16(qf[1], kf1, sa, 0, 0, 0);
      __builtin_amdgcn_s_setprio(0);
      s[c] = sa;
    }
    // p = exp(s*scale), TRUNCATED to bf16; l accumulates the truncated value
    // (numerator/denominator consistent -> no bias; phantom keys: p=1 exact)
#pragma unroll
    for (int c = 0; c < 4; ++c)
#pragma unroll
      for (int r = 0; r < 4; ++r) {
        union { float f; uint32_t u; } pv;
        pv.f = __expf(s[c][r] * scale);
        ldsp[wid][lg * 4 + r][c * 16 + lr] = (uint16_t)(pv.u >> 16);
        pv.u &= 0xffff0000u;
        lsum[r] += pv.f;
      }
    // ordering fence: scalar u16 writes -> vector bf16x8 read, same wave
    asm volatile("" ::: "memory");
    __builtin_amdgcn_sched_barrier(0);
    // O += P V
    __builtin_amdgcn_s_setprio(1);
#pragma unroll
    for (int kk = 0; kk < 2; ++kk) {
      bf16x8 pf = *(const bf16x8*)(pr + kk * 64);
#pragma unroll
      for (int cd = 0; cd < 4; ++cd) {
        bf16x8 vf = *(const bf16x8*)((kk ? vb1 : vb0) + cd * 2048);
        acc[cd] = __builtin_amdgcn_mfma_f32_16x16x32_bf16(pf, vf, acc[cd], 0, 0, 0);
      }
    }
    __builtin_amdgcn_s_setprio(0);
  }
  // final l reduce (16-lane groups), drop the 63 phantom keys, normalize, write O
#pragma unroll
  for (int r = 0; r < 4; ++r) {
    float l = lsum[r];
    l += __shfl_xor(l, 1); l += __shfl_xor(l, 2);
    l += __shfl_xor(l, 4); l += __shfl_xor(l, 8);
    l -= 63.0f;
    const float inv = 1.0f / l;
    const int n = qrow0 + lg * 4 + r;
    size_t base = ((size_t)b * NN + n) * DIMF + h * HD;
#pragma unroll
    for (int cd = 0; cd < 4; ++cd)
      o_ws[base + cd * 16 + lr] = f2b(acc[cd][r] * inv);
  }
}

extern "C" void kernel_launch(void* const* d_in, const int* in_sizes, int n_in,
                              void* d_out, int out_size, void* d_ws, size_t ws_size,
                              hipStream_t stream) {
  const float* x      = (const float*)d_in[0];
  const float* wqkv   = (const float*)d_in[1];
  const float* wout   = (const float*)d_in[2];
  const float* bout   = (const float*)d_in[3];
  // d_in[4] = void_q: unused (void query row is dropped by the reference)
  const float* voidk  = (const float*)d_in[5];
  const float* voidv  = (const float*)d_in[6];
  const float* trace  = (const float*)d_in[7];
  const float* factor = (const float*)d_in[8];
  float* out = (float*)d_out;           // reference output dtype is FP32

  uint16_t* ws    = (uint16_t*)d_ws;
  uint16_t* x_bf  = ws;                       // 2*2048*1024  = 4,194,304 elems
  uint16_t* o_ws  = x_bf;                     // ALIAS: x_bf dead after gemm<0>
  uint16_t* wqkvT = x_bf  + 4194304;          // 3072*1024    = 3,145,728
  uint16_t* woutT = wqkvT + 3145728;          // 1024*1024    = 1,048,576
  uint16_t* q_ws  = woutT + 1048576;          // 2*16*2048*64 = 4,194,304
  uint16_t* k_ws  = q_ws  + 4194304;          // 2*16*2112*64 = 4,325,376
  uint16_t* vt_ws = k_ws  + 4325376;          // 4,325,376   (total ~42.5 MB)

  prep_k<<<dim3(4608), dim3(256), 0, stream>>>(x, x_bf, voidk, voidv, k_ws, vt_ws);
  transpose2_k<<<dim3(96, 32, 2), dim3(256), 0, stream>>>(wqkv, wqkvT, wout, woutT);
  gemm_bt<0><<<dim3(3072 / 128, 4096 / 128), dim3(256), 0, stream>>>(
      x_bf, wqkvT, 1024, 3072, q_ws, k_ws, vt_ws, nullptr, nullptr);
  attn_k<<<dim3(HEADS * BB, NN / 64), dim3(256), 0, stream>>>(
      q_ws, k_ws, vt_ws, trace, factor, o_ws);
  gemm_bt<1><<<dim3(1024 / 128, 4096 / 128), dim3(256), 0, stream>>>(
      o_ws, woutT, 1024, 1024, nullptr, nullptr, nullptr, out, bout);
}

// Round 14
// 138.733 us; speedup vs baseline: 1.3518x; 1.1106x over previous
//
#include <hip/hip_runtime.h>
#include <stdint.h>

#define DIMF   1024
#define HEADS  16
#define HD     64
#define BB     2
#define NN     2048
#define NKP    2112   // 2049 keys padded to 33*64
#define NTILE  33

typedef __attribute__((ext_vector_type(8))) __bf16 bf16x8;
typedef __attribute__((ext_vector_type(4))) float  f32x4;

__device__ __forceinline__ float b2f(uint16_t h) {
  union { uint32_t u; float f; } v; v.u = ((uint32_t)h) << 16; return v.f;
}
__device__ __forceinline__ uint16_t f2b(float f) {
  union { float f; uint32_t u; } v; v.f = f;
  uint32_t r = v.u + 0x7FFFu + ((v.u >> 16) & 1u);
  return (uint16_t)(r >> 16);
}

// async global->LDS DMA, 16B per lane. LDS dest = wave-uniform base + lane*16.
__device__ __forceinline__ void gl_lds16(const void* g, void* l) {
  __builtin_amdgcn_global_load_lds(
      (const __attribute__((address_space(1))) void*)g,
      (__attribute__((address_space(3))) void*)l, 16, 0, 0);
}

// ---- merged preprocessing (single launch):
//   blocks [0,4096)        : cvt x (fp32) -> x_bf (bf16), float4 loads
//   blocks [4096,4608)     : void K/V row + zero padding
//   blocks [4608,7680)     : transpose wqkv 1024x3072 -> bf16 3072x1024
//   blocks [7680,8704)     : transpose wout 1024x1024 -> bf16 1024x1024
__global__ __launch_bounds__(256) void prep_k(const float* __restrict__ x,
                                              uint16_t* __restrict__ x_bf,
                                              const float* __restrict__ vk,
                                              const float* __restrict__ vv,
                                              uint16_t* __restrict__ k_ws,
                                              uint16_t* __restrict__ vt_ws,
                                              const float* __restrict__ wqkv,
                                              uint16_t* __restrict__ wqkvT,
                                              const float* __restrict__ wout,
                                              uint16_t* __restrict__ woutT) {
  __shared__ uint16_t tile[32][33];
  const int blk = blockIdx.x;
  if (blk < 4096) {
    int i = blk * 256 + threadIdx.x;             // < 1048576 float4s
    float4 v = *(const float4*)&x[(size_t)i * 4];
    uint16_t* d = x_bf + (size_t)i * 4;
    d[0] = f2b(v.x); d[1] = f2b(v.y); d[2] = f2b(v.z); d[3] = f2b(v.w);
  } else if (blk < 4608) {
    int idx = (blk - 4096) * 256 + threadIdx.x;  // 0 .. 131071
    int dd = idx & 63;
    int r  = (idx >> 6) & 63;      // padded key row 2048+r
    int bh = idx >> 12;            // 0..31
    int h  = bh & (HEADS - 1);
    uint16_t kv  = (r == 0) ? f2b(vk[h * HD + dd]) : (uint16_t)0;
    uint16_t vvv = (r == 0) ? f2b(vv[h * HD + dd]) : (uint16_t)0;
    k_ws[((size_t)bh * NKP + NN + r) * HD + dd]  = kv;
    vt_ws[((size_t)bh * HD + dd) * NKP + NN + r] = vvv;
  } else {
    int tb = blk - 4608;
    const float* src; uint16_t* dst; int N, bx, by;
    if (tb < 3072) { src = wqkv; dst = wqkvT; N = 3072; bx = (tb % 96) * 32; by = (tb / 96) * 32; }
    else { tb -= 3072; src = wout; dst = woutT; N = 1024; bx = (tb % 32) * 32; by = (tb / 32) * 32; }
    const int M = 1024;
    int xx = threadIdx.x & 31, y0 = (threadIdx.x >> 5) * 4;
#pragma unroll
    for (int i = 0; i < 4; ++i)
      tile[y0 + i][xx] = f2b(src[(size_t)(by + y0 + i) * N + bx + xx]);
    __syncthreads();
#pragma unroll
    for (int i = 0; i < 4; ++i)
      dst[(size_t)(bx + y0 + i) * M + by + xx] = tile[xx][y0 + i];
  }
}

// ---------------- GEMM: C[M,N] = A[M,K] * Bt[N,K]^T, bf16 in, fp32 acc ----------------
// EPI 0: scatter bf16 to Q [bh,2048,64], K [bh,2112,64], Vt [bh,64,2112]
// EPI 1: add fp32 bias, write FP32 row-major [M,Nout]
template<int EPI>
__global__ __launch_bounds__(256) void gemm_bt(const uint16_t* __restrict__ A,
                                               const uint16_t* __restrict__ Bt,
                                               int K, int Nout,
                                               uint16_t* __restrict__ o0,
                                               uint16_t* __restrict__ o1,
                                               uint16_t* __restrict__ o2,
                                               float* __restrict__ fo,
                                               const float* __restrict__ bias) {
  __shared__ uint16_t lds_a[128][32];   // linear: required by global_load_lds
  __shared__ uint16_t lds_b[128][32];
  const int m0 = blockIdx.y * 128, n0 = blockIdx.x * 128;
  const int tid = threadIdx.x, lane = tid & 63, wid = tid >> 6;
  const int wm = (wid >> 1) * 64, wn = (wid & 1) * 64;
  const int lr = lane & 15, lg = lane >> 4;
  f32x4 acc[4][4] = {};
  for (int k0 = 0; k0 < K; k0 += 32) {
    __syncthreads();
#pragma unroll
    for (int it = 0; it < 2; ++it) {
      const int chunk = wid * 2 + it;            // 0..7 (1 KiB each)
      const int o = chunk * 1024 + lane * 16;
      const int r = o >> 6, cb = o & 63;
      gl_lds16((const char*)&A[(size_t)(m0 + r) * K + k0] + cb,
               (char*)&lds_a[0][0] + chunk * 1024);
      gl_lds16((const char*)&Bt[(size_t)(n0 + r) * K + k0] + cb,
               (char*)&lds_b[0][0] + chunk * 1024);
    }
    __syncthreads();
    bf16x8 af[4], bf[4];
#pragma unroll
    for (int i = 0; i < 4; ++i)
      af[i] = *(const bf16x8*)((const char*)&lds_a[0][0] + (wm + i * 16 + lr) * 64 + lg * 16);
#pragma unroll
    for (int j = 0; j < 4; ++j)
      bf[j] = *(const bf16x8*)((const char*)&lds_b[0][0] + (wn + j * 16 + lr) * 64 + lg * 16);
#pragma unroll
    for (int i = 0; i < 4; ++i)
#pragma unroll
      for (int j = 0; j < 4; ++j)
        acc[i][j] = __builtin_amdgcn_mfma_f32_16x16x32_bf16(af[i], bf[j], acc[i][j], 0, 0, 0);
  }
#pragma unroll
  for (int i = 0; i < 4; ++i)
#pragma unroll
    for (int j = 0; j < 4; ++j)
#pragma unroll
      for (int r = 0; r < 4; ++r) {
        int mg = m0 + wm + i * 16 + lg * 4 + r;   // C row = m (m89 layout)
        int ng = n0 + wn + j * 16 + lr;            // C col = n
        float v = acc[i][j][r];
        if (EPI == 0) {
          int b = mg >> 11, n = mg & (NN - 1);
          int which = ng >> 10, rem = ng & (DIMF - 1), h = rem >> 6, dd = rem & 63;
          int bh = b * HEADS + h;
          uint16_t bv = f2b(v);
          if (which == 0)      o0[((size_t)bh * NN + n) * HD + dd] = bv;
          else if (which == 1) o1[((size_t)bh * NKP + n) * HD + dd] = bv;
          else                 o2[((size_t)bh * HD + dd) * NKP + n] = bv;  // V transposed
        } else {
          fo[(size_t)mg * Nout + ng] = v + bias[ng];   // FP32 output
        }
      }
}

// ---- flash attention: round-13 per-wave code, 8 WAVES/BLOCK (concurrency fix) ----
// 8 waves x 16 q-rows = 128 q/block; K/V staged ONCE per 128 q (per-wave staging
// cost halves). LDS 34.8 KB -> 4 blocks/CU allowed; grid 512 = 2 blocks/CU =
// 16 waves/CU (50% occ vs 35%). Same 2-barrier tile loop, same fragment maps,
// same truncated-P softmax, bh-fastest grid (L2-pinned K/V).
__global__ __launch_bounds__(512) void attn_k(const uint16_t* __restrict__ q_ws,
                                              const uint16_t* __restrict__ k_ws,
                                              const uint16_t* __restrict__ vt_ws,
                                              const float* __restrict__ trace,
                                              const float* __restrict__ factor,
                                              uint16_t* __restrict__ o_ws) {
  __shared__ uint16_t ldsk[64][64];      // [key][d]   128 B rows, swizzled cols
  __shared__ uint16_t ldsv[64][64];      // [d][key]   (from Vt), swizzled cols
  __shared__ uint16_t ldsp[8][16][72];   // per-wave P re-layout buffer (+pad)
  const int bh = blockIdx.x;             // FASTEST dim -> XCD = bh%8 (L2 locality)
  const int qb = blockIdx.y;
  const int h = bh & (HEADS - 1), b = bh >> 4;
  const int tid = threadIdx.x, lane = tid & 63, wid = tid >> 6;  // wid 0..7
  const int lr = lane & 15, lg = lane >> 4;

  const float temp  = fmaxf(1.0f + fabsf(trace[h]) * factor[h], 1.0f);
  const float scale = 0.03125f / temp;   // dim^-0.5 / temperature

  const int qrow0 = qb * 128 + wid * 16;
  const uint16_t* qrow = q_ws + ((size_t)bh * NN + qrow0 + lr) * HD;
  bf16x8 qf[2];
  qf[0] = *(const bf16x8*)(qrow + lg * 8);
  qf[1] = *(const bf16x8*)(qrow + 32 + lg * 8);

  // hoisted loop-invariant LDS read addresses (row = c*16+lr -> row&7 == lr&7)
  const int rsw = (lr & 7) << 4;
  const char* kb0 = (const char*)&ldsk[0][0] + lr * 128 + ((lg * 16) ^ rsw);
  const char* kb1 = (const char*)&ldsk[0][0] + lr * 128 + ((64 + lg * 16) ^ rsw);
  const char* vb0 = (const char*)&ldsv[0][0] + lr * 128 + ((lg * 16) ^ rsw);
  const char* vb1 = (const char*)&ldsv[0][0] + lr * 128 + ((64 + lg * 16) ^ rsw);
  const char* pr  = (const char*)&ldsp[wid][lr][lg * 8];

  f32x4 acc[4] = {};
  float lsum[4] = {0.f, 0.f, 0.f, 0.f};

  for (int t = 0; t < NTILE; ++t) {
    const int t0 = t * 64;
    __syncthreads();
    {
      const int chunk = wid;                    // 0..7 (1 KiB each), 1 pair/wave
      const int o = chunk * 1024 + lane * 16;
      const int r = o >> 7, cb = o & 127;       // 128 B per row
      const int scb = cb ^ ((r & 7) << 4);      // pre-swizzled source col
      gl_lds16((const char*)&k_ws[((size_t)bh * NKP + t0 + r) * HD] + scb,
               (char*)&ldsk[0][0] + chunk * 1024);
      gl_lds16((const char*)&vt_ws[((size_t)bh * HD + r) * NKP + t0] + scb,
               (char*)&ldsv[0][0] + chunk * 1024);
    }
    __syncthreads();

    // S = Q K^T (4 chunks of 16 keys)
    f32x4 s[4];
#pragma unroll
    for (int c = 0; c < 4; ++c) {
      bf16x8 kf0 = *(const bf16x8*)(kb0 + c * 2048);
      bf16x8 kf1 = *(const bf16x8*)(kb1 + c * 2048);
      f32x4 sa = {};
      __builtin_amdgcn_s_setprio(1);
      sa = __builtin_amdgcn_mfma_f32_16x16x32_bf16(qf[0], kf0, sa, 0, 0, 0);
      sa = __builtin_amdgcn_mfma_f32_16x16x32_bf16(qf[1], kf1, sa, 0, 0, 0);
      __builtin_amdgcn_s_setprio(0);
      s[c] = sa;
    }
    // p = exp(s*scale), TRUNCATED to bf16; l accumulates the truncated value
#pragma unroll
    for (int c = 0; c < 4; ++c)
#pragma unroll
      for (int r = 0; r < 4; ++r) {
        union { float f; uint32_t u; } pv;
        pv.f = __expf(s[c][r] * scale);
        ldsp[wid][lg * 4 + r][c * 16 + lr] = (uint16_t)(pv.u >> 16);
        pv.u &= 0xffff0000u;
        lsum[r] += pv.f;
      }
    // ordering fence: scalar u16 writes -> vector bf16x8 read, same wave
    asm volatile("" ::: "memory");
    __builtin_amdgcn_sched_barrier(0);
    // O += P V
    __builtin_amdgcn_s_setprio(1);
#pragma unroll
    for (int kk = 0; kk < 2; ++kk) {
      bf16x8 pf = *(const bf16x8*)(pr + kk * 64);
#pragma unroll
      for (int cd = 0; cd < 4; ++cd) {
        bf16x8 vf = *(const bf16x8*)((kk ? vb1 : vb0) + cd * 2048);
        acc[cd] = __builtin_amdgcn_mfma_f32_16x16x32_bf16(pf, vf, acc[cd], 0, 0, 0);
      }
    }
    __builtin_amdgcn_s_setprio(0);
  }
  // final l reduce (16-lane groups), drop the 63 phantom keys, normalize, write O
#pragma unroll
  for (int r = 0; r < 4; ++r) {
    float l = lsum[r];
    l += __shfl_xor(l, 1); l += __shfl_xor(l, 2);
    l += __shfl_xor(l, 4); l += __shfl_xor(l, 8);
    l -= 63.0f;
    const float inv = 1.0f / l;
    const int n = qrow0 + lg * 4 + r;
    size_t base = ((size_t)b * NN + n) * DIMF + h * HD;
#pragma unroll
    for (int cd = 0; cd < 4; ++cd)
      o_ws[base + cd * 16 + lr] = f2b(acc[cd][r] * inv);
  }
}

extern "C" void kernel_launch(void* const* d_in, const int* in_sizes, int n_in,
                              void* d_out, int out_size, void* d_ws, size_t ws_size,
                              hipStream_t stream) {
  const float* x      = (const float*)d_in[0];
  const float* wqkv   = (const float*)d_in[1];
  const float* wout   = (const float*)d_in[2];
  const float* bout   = (const float*)d_in[3];
  // d_in[4] = void_q: unused (void query row is dropped by the reference)
  const float* voidk  = (const float*)d_in[5];
  const float* voidv  = (const float*)d_in[6];
  const float* trace  = (const float*)d_in[7];
  const float* factor = (const float*)d_in[8];
  float* out = (float*)d_out;           // reference output dtype is FP32

  uint16_t* ws    = (uint16_t*)d_ws;
  uint16_t* x_bf  = ws;                       // 2*2048*1024  = 4,194,304 elems
  uint16_t* o_ws  = x_bf;                     // ALIAS: x_bf dead after gemm<0>
  uint16_t* wqkvT = x_bf  + 4194304;          // 3072*1024    = 3,145,728
  uint16_t* woutT = wqkvT + 3145728;          // 1024*1024    = 1,048,576
  uint16_t* q_ws  = woutT + 1048576;          // 2*16*2048*64 = 4,194,304
  uint16_t* k_ws  = q_ws  + 4194304;          // 2*16*2112*64 = 4,325,376
  uint16_t* vt_ws = k_ws  + 4325376;          // 4,325,376   (total ~42.5 MB)

  prep_k<<<dim3(8704), dim3(256), 0, stream>>>(x, x_bf, voidk, voidv, k_ws, vt_ws,
                                               wqkv, wqkvT, wout, woutT);
  gemm_bt<0><<<dim3(3072 / 128, 4096 / 128), dim3(256), 0, stream>>>(
      x_bf, wqkvT, 1024, 3072, q_ws, k_ws, vt_ws, nullptr, nullptr);
  attn_k<<<dim3(HEADS * BB, NN / 128), dim3(512), 0, stream>>>(
      q_ws, k_ws, vt_ws, trace, factor, o_ws);
  gemm_bt<1><<<dim3(1024 / 128, 4096 / 128), dim3(256), 0, stream>>>(
      o_ws, woutT, 1024, 1024, nullptr, nullptr, nullptr, out, bout);
}

// Round 15
// 135.864 us; speedup vs baseline: 1.3803x; 1.0211x over previous
//
#include <hip/hip_runtime.h>
#include <stdint.h>

#define DIMF   1024
#define HEADS  16
#define HD     64
#define BB     2
#define NN     2048
#define NKP    2112   // 2049 keys padded to 33*64
#define NTILE  33

typedef __attribute__((ext_vector_type(8))) __bf16 bf16x8;
typedef __attribute__((ext_vector_type(4))) float  f32x4;

__device__ __forceinline__ float b2f(uint16_t h) {
  union { uint32_t u; float f; } v; v.u = ((uint32_t)h) << 16; return v.f;
}
__device__ __forceinline__ uint16_t f2b(float f) {
  union { float f; uint32_t u; } v; v.f = f;
  uint32_t r = v.u + 0x7FFFu + ((v.u >> 16) & 1u);
  return (uint16_t)(r >> 16);
}

// async global->LDS DMA, 16B per lane. LDS dest = wave-uniform base + lane*16.
__device__ __forceinline__ void gl_lds16(const void* g, void* l) {
  __builtin_amdgcn_global_load_lds(
      (const __attribute__((address_space(1))) void*)g,
      (__attribute__((address_space(3))) void*)l, 16, 0, 0);
}

// ---- merged preprocessing (single launch):
//   blocks [0,4096)        : cvt x (fp32) -> x_bf (bf16), float4 loads
//   blocks [4096,4608)     : void K/V row + zero padding
//   blocks [4608,7680)     : transpose wqkv 1024x3072 -> bf16 3072x1024
//   blocks [7680,8704)     : transpose wout 1024x1024 -> bf16 1024x1024
__global__ __launch_bounds__(256) void prep_k(const float* __restrict__ x,
                                              uint16_t* __restrict__ x_bf,
                                              const float* __restrict__ vk,
                                              const float* __restrict__ vv,
                                              uint16_t* __restrict__ k_ws,
                                              uint16_t* __restrict__ vt_ws,
                                              const float* __restrict__ wqkv,
                                              uint16_t* __restrict__ wqkvT,
                                              const float* __restrict__ wout,
                                              uint16_t* __restrict__ woutT) {
  __shared__ uint16_t tile[32][33];
  const int blk = blockIdx.x;
  if (blk < 4096) {
    int i = blk * 256 + threadIdx.x;             // < 1048576 float4s
    float4 v = *(const float4*)&x[(size_t)i * 4];
    uint16_t* d = x_bf + (size_t)i * 4;
    d[0] = f2b(v.x); d[1] = f2b(v.y); d[2] = f2b(v.z); d[3] = f2b(v.w);
  } else if (blk < 4608) {
    int idx = (blk - 4096) * 256 + threadIdx.x;  // 0 .. 131071
    int dd = idx & 63;
    int r  = (idx >> 6) & 63;      // padded key row 2048+r
    int bh = idx >> 12;            // 0..31
    int h  = bh & (HEADS - 1);
    uint16_t kv  = (r == 0) ? f2b(vk[h * HD + dd]) : (uint16_t)0;
    uint16_t vvv = (r == 0) ? f2b(vv[h * HD + dd]) : (uint16_t)0;
    k_ws[((size_t)bh * NKP + NN + r) * HD + dd]  = kv;
    vt_ws[((size_t)bh * HD + dd) * NKP + NN + r] = vvv;
  } else {
    int tb = blk - 4608;
    const float* src; uint16_t* dst; int N, bx, by;
    if (tb < 3072) { src = wqkv; dst = wqkvT; N = 3072; bx = (tb % 96) * 32; by = (tb / 96) * 32; }
    else { tb -= 3072; src = wout; dst = woutT; N = 1024; bx = (tb % 32) * 32; by = (tb / 32) * 32; }
    const int M = 1024;
    int xx = threadIdx.x & 31, y0 = (threadIdx.x >> 5) * 4;
#pragma unroll
    for (int i = 0; i < 4; ++i)
      tile[y0 + i][xx] = f2b(src[(size_t)(by + y0 + i) * N + bx + xx]);
    __syncthreads();
#pragma unroll
    for (int i = 0; i < 4; ++i)
      dst[(size_t)(bx + y0 + i) * M + by + xx] = tile[xx][y0 + i];
  }
}

// ------------- GEMM: C[M,N] = A[M,K] * Bt[N,K]^T, bf16 in, fp32 acc -------------
// BK=64: halves the per-K-step barrier/vmcnt-drain count vs BK=32 (the 2-phase
// critical path per m233). LDS rows are 128 B -> T2/G21 XOR swizzle (attn-proven
// pattern): pre-swizzled DMA source col + swizzled ds_read col, (row&7)<<4.
// EPI 0: scatter bf16 to Q [bh,2048,64], K [bh,2112,64], Vt [bh,64,2112]
// EPI 1: add fp32 bias, write FP32 row-major [M,Nout]
template<int EPI>
__global__ __launch_bounds__(256) void gemm_bt(const uint16_t* __restrict__ A,
                                               const uint16_t* __restrict__ Bt,
                                               int K, int Nout,
                                               uint16_t* __restrict__ o0,
                                               uint16_t* __restrict__ o1,
                                               uint16_t* __restrict__ o2,
                                               float* __restrict__ fo,
                                               const float* __restrict__ bias) {
  __shared__ uint16_t lds_a[128][64];   // 16 KB, linear dest for global_load_lds
  __shared__ uint16_t lds_b[128][64];   // 16 KB
  const int m0 = blockIdx.y * 128, n0 = blockIdx.x * 128;
  const int tid = threadIdx.x, lane = tid & 63, wid = tid >> 6;
  const int wm = (wid >> 1) * 64, wn = (wid & 1) * 64;
  const int lr = lane & 15, lg = lane >> 4;

  // hoisted swizzled read offsets: row = (wm|wn) + i*16 + lr -> row&7 == lr&7
  const int rsw = (lr & 7) << 4;
  const int rc0 = (lg * 16) ^ rsw;          // kk=0 col byte
  const int rc1 = (64 + lg * 16) ^ rsw;     // kk=1 col byte

  f32x4 acc[4][4] = {};
  for (int k0 = 0; k0 < K; k0 += 64) {
    __syncthreads();
#pragma unroll
    for (int it = 0; it < 4; ++it) {
      const int chunk = wid * 4 + it;            // 0..15 (1 KiB each)
      const int o = chunk * 1024 + lane * 16;
      const int r = o >> 7, cb = o & 127;        // 128 B per row
      const int scb = cb ^ ((r & 7) << 4);       // pre-swizzled source col
      gl_lds16((const char*)&A[(size_t)(m0 + r) * K + k0] + scb,
               (char*)&lds_a[0][0] + chunk * 1024);
      gl_lds16((const char*)&Bt[(size_t)(n0 + r) * K + k0] + scb,
               (char*)&lds_b[0][0] + chunk * 1024);
    }
    __syncthreads();
    bf16x8 af[4][2], bf[4][2];
#pragma unroll
    for (int i = 0; i < 4; ++i) {
      const char* ra = (const char*)&lds_a[0][0] + (wm + i * 16 + lr) * 128;
      af[i][0] = *(const bf16x8*)(ra + rc0);
      af[i][1] = *(const bf16x8*)(ra + rc1);
    }
#pragma unroll
    for (int j = 0; j < 4; ++j) {
      const char* rb = (const char*)&lds_b[0][0] + (wn + j * 16 + lr) * 128;
      bf[j][0] = *(const bf16x8*)(rb + rc0);
      bf[j][1] = *(const bf16x8*)(rb + rc1);
    }
#pragma unroll
    for (int kk = 0; kk < 2; ++kk)
#pragma unroll
      for (int i = 0; i < 4; ++i)
#pragma unroll
        for (int j = 0; j < 4; ++j)
          acc[i][j] = __builtin_amdgcn_mfma_f32_16x16x32_bf16(af[i][kk], bf[j][kk],
                                                              acc[i][j], 0, 0, 0);
  }
#pragma unroll
  for (int i = 0; i < 4; ++i)
#pragma unroll
    for (int j = 0; j < 4; ++j)
#pragma unroll
      for (int r = 0; r < 4; ++r) {
        int mg = m0 + wm + i * 16 + lg * 4 + r;   // C row = m (m89 layout)
        int ng = n0 + wn + j * 16 + lr;            // C col = n
        float v = acc[i][j][r];
        if (EPI == 0) {
          int b = mg >> 11, n = mg & (NN - 1);
          int which = ng >> 10, rem = ng & (DIMF - 1), h = rem >> 6, dd = rem & 63;
          int bh = b * HEADS + h;
          uint16_t bv = f2b(v);
          if (which == 0)      o0[((size_t)bh * NN + n) * HD + dd] = bv;
          else if (which == 1) o1[((size_t)bh * NKP + n) * HD + dd] = bv;
          else                 o2[((size_t)bh * HD + dd) * NKP + n] = bv;  // V transposed
        } else {
          fo[(size_t)mg * Nout + ng] = v + bias[ng];   // FP32 output
        }
      }
}

// ---- flash attention: FROZEN round-14 kernel (8 waves x 16 q, LDS-floor ~64%) ----
__global__ __launch_bounds__(512) void attn_k(const uint16_t* __restrict__ q_ws,
                                              const uint16_t* __restrict__ k_ws,
                                              const uint16_t* __restrict__ vt_ws,
                                              const float* __restrict__ trace,
                                              const float* __restrict__ factor,
                                              uint16_t* __restrict__ o_ws) {
  __shared__ uint16_t ldsk[64][64];      // [key][d]   128 B rows, swizzled cols
  __shared__ uint16_t ldsv[64][64];      // [d][key]   (from Vt), swizzled cols
  __shared__ uint16_t ldsp[8][16][72];   // per-wave P re-layout buffer (+pad)
  const int bh = blockIdx.x;             // FASTEST dim -> XCD = bh%8 (L2 locality)
  const int qb = blockIdx.y;
  const int h = bh & (HEADS - 1), b = bh >> 4;
  const int tid = threadIdx.x, lane = tid & 63, wid = tid >> 6;  // wid 0..7
  const int lr = lane & 15, lg = lane >> 4;

  const float temp  = fmaxf(1.0f + fabsf(trace[h]) * factor[h], 1.0f);
  const float scale = 0.03125f / temp;   // dim^-0.5 / temperature

  const int qrow0 = qb * 128 + wid * 16;
  const uint16_t* qrow = q_ws + ((size_t)bh * NN + qrow0 + lr) * HD;
  bf16x8 qf[2];
  qf[0] = *(const bf16x8*)(qrow + lg * 8);
  qf[1] = *(const bf16x8*)(qrow + 32 + lg * 8);

  // hoisted loop-invariant LDS read addresses (row = c*16+lr -> row&7 == lr&7)
  const int rsw = (lr & 7) << 4;
  const char* kb0 = (const char*)&ldsk[0][0] + lr * 128 + ((lg * 16) ^ rsw);
  const char* kb1 = (const char*)&ldsk[0][0] + lr * 128 + ((64 + lg * 16) ^ rsw);
  const char* vb0 = (const char*)&ldsv[0][0] + lr * 128 + ((lg * 16) ^ rsw);
  const char* vb1 = (const char*)&ldsv[0][0] + lr * 128 + ((64 + lg * 16) ^ rsw);
  const char* pr  = (const char*)&ldsp[wid][lr][lg * 8];

  f32x4 acc[4] = {};
  float lsum[4] = {0.f, 0.f, 0.f, 0.f};

  for (int t = 0; t < NTILE; ++t) {
    const int t0 = t * 64;
    __syncthreads();
    {
      const int chunk = wid;                    // 0..7 (1 KiB each), 1 pair/wave
      const int o = chunk * 1024 + lane * 16;
      const int r = o >> 7, cb = o & 127;       // 128 B per row
      const int scb = cb ^ ((r & 7) << 4);      // pre-swizzled source col
      gl_lds16((const char*)&k_ws[((size_t)bh * NKP + t0 + r) * HD] + scb,
               (char*)&ldsk[0][0] + chunk * 1024);
      gl_lds16((const char*)&vt_ws[((size_t)bh * HD + r) * NKP + t0] + scb,
               (char*)&ldsv[0][0] + chunk * 1024);
    }
    __syncthreads();

    // S = Q K^T (4 chunks of 16 keys)
    f32x4 s[4];
#pragma unroll
    for (int c = 0; c < 4; ++c) {
      bf16x8 kf0 = *(const bf16x8*)(kb0 + c * 2048);
      bf16x8 kf1 = *(const bf16x8*)(kb1 + c * 2048);
      f32x4 sa = {};
      __builtin_amdgcn_s_setprio(1);
      sa = __builtin_amdgcn_mfma_f32_16x16x32_bf16(qf[0], kf0, sa, 0, 0, 0);
      sa = __builtin_amdgcn_mfma_f32_16x16x32_bf16(qf[1], kf1, sa, 0, 0, 0);
      __builtin_amdgcn_s_setprio(0);
      s[c] = sa;
    }
    // p = exp(s*scale), TRUNCATED to bf16; l accumulates the truncated value
#pragma unroll
    for (int c = 0; c < 4; ++c)
#pragma unroll
      for (int r = 0; r < 4; ++r) {
        union { float f; uint32_t u; } pv;
        pv.f = __expf(s[c][r] * scale);
        ldsp[wid][lg * 4 + r][c * 16 + lr] = (uint16_t)(pv.u >> 16);
        pv.u &= 0xffff0000u;
        lsum[r] += pv.f;
      }
    // ordering fence: scalar u16 writes -> vector bf16x8 read, same wave
    asm volatile("" ::: "memory");
    __builtin_amdgcn_sched_barrier(0);
    // O += P V
    __builtin_amdgcn_s_setprio(1);
#pragma unroll
    for (int kk = 0; kk < 2; ++kk) {
      bf16x8 pf = *(const bf16x8*)(pr + kk * 64);
#pragma unroll
      for (int cd = 0; cd < 4; ++cd) {
        bf16x8 vf = *(const bf16x8*)((kk ? vb1 : vb0) + cd * 2048);
        acc[cd] = __builtin_amdgcn_mfma_f32_16x16x32_bf16(pf, vf, acc[cd], 0, 0, 0);
      }
    }
    __builtin_amdgcn_s_setprio(0);
  }
  // final l reduce (16-lane groups), drop the 63 phantom keys, normalize, write O
#pragma unroll
  for (int r = 0; r < 4; ++r) {
    float l = lsum[r];
    l += __shfl_xor(l, 1); l += __shfl_xor(l, 2);
    l += __shfl_xor(l, 4); l += __shfl_xor(l, 8);
    l -= 63.0f;
    const float inv = 1.0f / l;
    const int n = qrow0 + lg * 4 + r;
    size_t base = ((size_t)b * NN + n) * DIMF + h * HD;
#pragma unroll
    for (int cd = 0; cd < 4; ++cd)
      o_ws[base + cd * 16 + lr] = f2b(acc[cd][r] * inv);
  }
}

extern "C" void kernel_launch(void* const* d_in, const int* in_sizes, int n_in,
                              void* d_out, int out_size, void* d_ws, size_t ws_size,
                              hipStream_t stream) {
  const float* x      = (const float*)d_in[0];
  const float* wqkv   = (const float*)d_in[1];
  const float* wout   = (const float*)d_in[2];
  const float* bout   = (const float*)d_in[3];
  // d_in[4] = void_q: unused (void query row is dropped by the reference)
  const float* voidk  = (const float*)d_in[5];
  const float* voidv  = (const float*)d_in[6];
  const float* trace  = (const float*)d_in[7];
  const float* factor = (const float*)d_in[8];
  float* out = (float*)d_out;           // reference output dtype is FP32

  uint16_t* ws    = (uint16_t*)d_ws;
  uint16_t* x_bf  = ws;                       // 2*2048*1024  = 4,194,304 elems
  uint16_t* o_ws  = x_bf;                     // ALIAS: x_bf dead after gemm<0>
  uint16_t* wqkvT = x_bf  + 4194304;          // 3072*1024    = 3,145,728
  uint16_t* woutT = wqkvT + 3145728;          // 1024*1024    = 1,048,576
  uint16_t* q_ws  = woutT + 1048576;          // 2*16*2048*64 = 4,194,304
  uint16_t* k_ws  = q_ws  + 4194304;          // 2*16*2112*64 = 4,325,376
  uint16_t* vt_ws = k_ws  + 4325376;          // 4,325,376   (total ~42.5 MB)

  prep_k<<<dim3(8704), dim3(256), 0, stream>>>(x, x_bf, voidk, voidv, k_ws, vt_ws,
                                               wqkv, wqkvT, wout, woutT);
  gemm_bt<0><<<dim3(3072 / 128, 4096 / 128), dim3(256), 0, stream>>>(
      x_bf, wqkvT, 1024, 3072, q_ws, k_ws, vt_ws, nullptr, nullptr);
  attn_k<<<dim3(HEADS * BB, NN / 128), dim3(512), 0, stream>>>(
      q_ws, k_ws, vt_ws, trace, factor, o_ws);
  gemm_bt<1><<<dim3(1024 / 128, 4096 / 128), dim3(256), 0, stream>>>(
      o_ws, woutT, 1024, 1024, nullptr, nullptr, nullptr, out, bout);
}

// Round 16
// 129.168 us; speedup vs baseline: 1.4519x; 1.0518x over previous
//
#include <hip/hip_runtime.h>
#include <stdint.h>

#define DIMF   1024
#define HEADS  16
#define HD     64
#define BB     2
#define NN     2048
#define NKP    2112   // 2049 keys padded to 33*64
#define NTILE  33

typedef __attribute__((ext_vector_type(8))) __bf16 bf16x8;
typedef __attribute__((ext_vector_type(4))) float  f32x4;

__device__ __forceinline__ float b2f(uint16_t h) {
  union { uint32_t u; float f; } v; v.u = ((uint32_t)h) << 16; return v.f;
}
__device__ __forceinline__ uint16_t f2b(float f) {
  union { float f; uint32_t u; } v; v.f = f;
  uint32_t r = v.u + 0x7FFFu + ((v.u >> 16) & 1u);
  return (uint16_t)(r >> 16);
}

// async global->LDS DMA, 16B per lane. LDS dest = wave-uniform base + lane*16.
__device__ __forceinline__ void gl_lds16(const void* g, void* l) {
  __builtin_amdgcn_global_load_lds(
      (const __attribute__((address_space(1))) void*)g,
      (__attribute__((address_space(3))) void*)l, 16, 0, 0);
}

// ---- merged preprocessing (single launch):
//   blocks [0,4096)        : cvt x (fp32) -> x_bf (bf16), float4 loads
//   blocks [4096,4608)     : void K/V row + zero padding
//   blocks [4608,7680)     : transpose wqkv 1024x3072 -> bf16 3072x1024
//   blocks [7680,8704)     : transpose wout 1024x1024 -> bf16 1024x1024
__global__ __launch_bounds__(256) void prep_k(const float* __restrict__ x,
                                              uint16_t* __restrict__ x_bf,
                                              const float* __restrict__ vk,
                                              const float* __restrict__ vv,
                                              uint16_t* __restrict__ k_ws,
                                              uint16_t* __restrict__ vt_ws,
                                              const float* __restrict__ wqkv,
                                              uint16_t* __restrict__ wqkvT,
                                              const float* __restrict__ wout,
                                              uint16_t* __restrict__ woutT) {
  __shared__ uint16_t tile[32][33];
  const int blk = blockIdx.x;
  if (blk < 4096) {
    int i = blk * 256 + threadIdx.x;             // < 1048576 float4s
    float4 v = *(const float4*)&x[(size_t)i * 4];
    uint16_t* d = x_bf + (size_t)i * 4;
    d[0] = f2b(v.x); d[1] = f2b(v.y); d[2] = f2b(v.z); d[3] = f2b(v.w);
  } else if (blk < 4608) {
    int idx = (blk - 4096) * 256 + threadIdx.x;  // 0 .. 131071
    int dd = idx & 63;
    int r  = (idx >> 6) & 63;      // padded key row 2048+r
    int bh = idx >> 12;            // 0..31
    int h  = bh & (HEADS - 1);
    uint16_t kv  = (r == 0) ? f2b(vk[h * HD + dd]) : (uint16_t)0;
    uint16_t vvv = (r == 0) ? f2b(vv[h * HD + dd]) : (uint16_t)0;
    k_ws[((size_t)bh * NKP + NN + r) * HD + dd]  = kv;
    vt_ws[((size_t)bh * HD + dd) * NKP + NN + r] = vvv;
  } else {
    int tb = blk - 4608;
    const float* src; uint16_t* dst; int N, bx, by;
    if (tb < 3072) { src = wqkv; dst = wqkvT; N = 3072; bx = (tb % 96) * 32; by = (tb / 96) * 32; }
    else { tb -= 3072; src = wout; dst = woutT; N = 1024; bx = (tb % 32) * 32; by = (tb / 32) * 32; }
    const int M = 1024;
    int xx = threadIdx.x & 31, y0 = (threadIdx.x >> 5) * 4;
#pragma unroll
    for (int i = 0; i < 4; ++i)
      tile[y0 + i][xx] = f2b(src[(size_t)(by + y0 + i) * N + bx + xx]);
    __syncthreads();
#pragma unroll
    for (int i = 0; i < 4; ++i)
      dst[(size_t)(bx + y0 + i) * M + by + xx] = tile[xx][y0 + i];
  }
}

// ------------- GEMM0: C[M,N] = A[M,K] * Bt[N,K]^T, 128x128 tile, BK=64 -------------
// Scatter epilogue: bf16 Q [bh,2048,64], K [bh,2112,64], Vt [bh,64,2112]
__global__ __launch_bounds__(256) void gemm0_k(const uint16_t* __restrict__ A,
                                               const uint16_t* __restrict__ Bt,
                                               int K,
                                               uint16_t* __restrict__ o0,
                                               uint16_t* __restrict__ o1,
                                               uint16_t* __restrict__ o2) {
  __shared__ uint16_t lds_a[128][64];   // 16 KB, linear dest for global_load_lds
  __shared__ uint16_t lds_b[128][64];   // 16 KB
  const int m0 = blockIdx.y * 128, n0 = blockIdx.x * 128;
  const int tid = threadIdx.x, lane = tid & 63, wid = tid >> 6;
  const int wm = (wid >> 1) * 64, wn = (wid & 1) * 64;
  const int lr = lane & 15, lg = lane >> 4;

  const int rsw = (lr & 7) << 4;
  const int rc0 = (lg * 16) ^ rsw;
  const int rc1 = (64 + lg * 16) ^ rsw;

  f32x4 acc[4][4] = {};
  for (int k0 = 0; k0 < K; k0 += 64) {
    __syncthreads();
#pragma unroll
    for (int it = 0; it < 4; ++it) {
      const int chunk = wid * 4 + it;            // 0..15 (1 KiB each)
      const int o = chunk * 1024 + lane * 16;
      const int r = o >> 7, cb = o & 127;        // 128 B per row
      const int scb = cb ^ ((r & 7) << 4);       // pre-swizzled source col
      gl_lds16((const char*)&A[(size_t)(m0 + r) * K + k0] + scb,
               (char*)&lds_a[0][0] + chunk * 1024);
      gl_lds16((const char*)&Bt[(size_t)(n0 + r) * K + k0] + scb,
               (char*)&lds_b[0][0] + chunk * 1024);
    }
    __syncthreads();
    bf16x8 af[4][2], bf[4][2];
#pragma unroll
    for (int i = 0; i < 4; ++i) {
      const char* ra = (const char*)&lds_a[0][0] + (wm + i * 16 + lr) * 128;
      af[i][0] = *(const bf16x8*)(ra + rc0);
      af[i][1] = *(const bf16x8*)(ra + rc1);
    }
#pragma unroll
    for (int j = 0; j < 4; ++j) {
      const char* rb = (const char*)&lds_b[0][0] + (wn + j * 16 + lr) * 128;
      bf[j][0] = *(const bf16x8*)(rb + rc0);
      bf[j][1] = *(const bf16x8*)(rb + rc1);
    }
#pragma unroll
    for (int kk = 0; kk < 2; ++kk)
#pragma unroll
      for (int i = 0; i < 4; ++i)
#pragma unroll
        for (int j = 0; j < 4; ++j)
          acc[i][j] = __builtin_amdgcn_mfma_f32_16x16x32_bf16(af[i][kk], bf[j][kk],
                                                              acc[i][j], 0, 0, 0);
  }
#pragma unroll
  for (int i = 0; i < 4; ++i)
#pragma unroll
    for (int j = 0; j < 4; ++j)
#pragma unroll
      for (int r = 0; r < 4; ++r) {
        int mg = m0 + wm + i * 16 + lg * 4 + r;   // C row = m (m89 layout)
        int ng = n0 + wn + j * 16 + lr;            // C col = n
        int b = mg >> 11, n = mg & (NN - 1);
        int which = ng >> 10, rem = ng & (DIMF - 1), h = rem >> 6, dd = rem & 63;
        int bh = b * HEADS + h;
        uint16_t bv = f2b(acc[i][j][r]);
        if (which == 0)      o0[((size_t)bh * NN + n) * HD + dd] = bv;
        else if (which == 1) o1[((size_t)bh * NKP + n) * HD + dd] = bv;
        else                 o2[((size_t)bh * HD + dd) * NKP + n] = bv;  // V transposed
      }
}

// ------------- GEMM1: out[M,1024] = A[M,K] * Bt[1024,K]^T + bias, FP32 out -------------
// BM=64, BN=128 -> grid 8x64 = 512 blocks = 2 blocks/CU (was 256 = 1/CU: the
// 12.5%-occupancy cripple). Wave tile 32x64 (acc[2][4]); same staging/swizzle
// idioms as gemm0.
__global__ __launch_bounds__(256) void gemm1_k(const uint16_t* __restrict__ A,
                                               const uint16_t* __restrict__ Bt,
                                               int K,
                                               float* __restrict__ fo,
                                               const float* __restrict__ bias) {
  __shared__ uint16_t lds_a[64][64];    // 8 KB
  __shared__ uint16_t lds_b[128][64];   // 16 KB
  const int m0 = blockIdx.y * 64, n0 = blockIdx.x * 128;
  const int tid = threadIdx.x, lane = tid & 63, wid = tid >> 6;
  const int wm = (wid >> 1) * 32, wn = (wid & 1) * 64;
  const int lr = lane & 15, lg = lane >> 4;

  const int rsw = (lr & 7) << 4;
  const int rc0 = (lg * 16) ^ rsw;
  const int rc1 = (64 + lg * 16) ^ rsw;

  f32x4 acc[2][4] = {};
  for (int k0 = 0; k0 < K; k0 += 64) {
    __syncthreads();
#pragma unroll
    for (int it = 0; it < 6; ++it) {
      const int c = wid * 6 + it;                // 0..23 (1 KiB each): 8 A + 16 B
      const int o = (c & 7) * 1024 + lane * 16;  // within-region offset for A
      if (c < 8) {
        const int r = o >> 7, cb = o & 127;
        const int scb = cb ^ ((r & 7) << 4);
        gl_lds16((const char*)&A[(size_t)(m0 + r) * K + k0] + scb,
                 (char*)&lds_a[0][0] + c * 1024);
      } else {
        const int o2 = (c - 8) * 1024 + lane * 16;
        const int r = o2 >> 7, cb = o2 & 127;
        const int scb = cb ^ ((r & 7) << 4);
        gl_lds16((const char*)&Bt[(size_t)(n0 + r) * K + k0] + scb,
                 (char*)&lds_b[0][0] + (c - 8) * 1024);
      }
    }
    __syncthreads();
    bf16x8 af[2][2], bf[4][2];
#pragma unroll
    for (int i = 0; i < 2; ++i) {
      const char* ra = (const char*)&lds_a[0][0] + (wm + i * 16 + lr) * 128;
      af[i][0] = *(const bf16x8*)(ra + rc0);
      af[i][1] = *(const bf16x8*)(ra + rc1);
    }
#pragma unroll
    for (int j = 0; j < 4; ++j) {
      const char* rb = (const char*)&lds_b[0][0] + (wn + j * 16 + lr) * 128;
      bf[j][0] = *(const bf16x8*)(rb + rc0);
      bf[j][1] = *(const bf16x8*)(rb + rc1);
    }
#pragma unroll
    for (int kk = 0; kk < 2; ++kk)
#pragma unroll
      for (int i = 0; i < 2; ++i)
#pragma unroll
        for (int j = 0; j < 4; ++j)
          acc[i][j] = __builtin_amdgcn_mfma_f32_16x16x32_bf16(af[i][kk], bf[j][kk],
                                                              acc[i][j], 0, 0, 0);
  }
#pragma unroll
  for (int i = 0; i < 2; ++i)
#pragma unroll
    for (int j = 0; j < 4; ++j)
#pragma unroll
      for (int r = 0; r < 4; ++r) {
        int mg = m0 + wm + i * 16 + lg * 4 + r;
        int ng = n0 + wn + j * 16 + lr;
        fo[(size_t)mg * DIMF + ng] = acc[i][j][r] + bias[ng];
      }
}

// ---- flash attention: FROZEN round-14 kernel (8 waves x 16 q, LDS-floor ~64%) ----
__global__ __launch_bounds__(512) void attn_k(const uint16_t* __restrict__ q_ws,
                                              const uint16_t* __restrict__ k_ws,
                                              const uint16_t* __restrict__ vt_ws,
                                              const float* __restrict__ trace,
                                              const float* __restrict__ factor,
                                              uint16_t* __restrict__ o_ws) {
  __shared__ uint16_t ldsk[64][64];      // [key][d]   128 B rows, swizzled cols
  __shared__ uint16_t ldsv[64][64];      // [d][key]   (from Vt), swizzled cols
  __shared__ uint16_t ldsp[8][16][72];   // per-wave P re-layout buffer (+pad)
  const int bh = blockIdx.x;             // FASTEST dim -> XCD = bh%8 (L2 locality)
  const int qb = blockIdx.y;
  const int h = bh & (HEADS - 1), b = bh >> 4;
  const int tid = threadIdx.x, lane = tid & 63, wid = tid >> 6;  // wid 0..7
  const int lr = lane & 15, lg = lane >> 4;

  const float temp  = fmaxf(1.0f + fabsf(trace[h]) * factor[h], 1.0f);
  const float scale = 0.03125f / temp;   // dim^-0.5 / temperature

  const int qrow0 = qb * 128 + wid * 16;
  const uint16_t* qrow = q_ws + ((size_t)bh * NN + qrow0 + lr) * HD;
  bf16x8 qf[2];
  qf[0] = *(const bf16x8*)(qrow + lg * 8);
  qf[1] = *(const bf16x8*)(qrow + 32 + lg * 8);

  // hoisted loop-invariant LDS read addresses (row = c*16+lr -> row&7 == lr&7)
  const int rsw = (lr & 7) << 4;
  const char* kb0 = (const char*)&ldsk[0][0] + lr * 128 + ((lg * 16) ^ rsw);
  const char* kb1 = (const char*)&ldsk[0][0] + lr * 128 + ((64 + lg * 16) ^ rsw);
  const char* vb0 = (const char*)&ldsv[0][0] + lr * 128 + ((lg * 16) ^ rsw);
  const char* vb1 = (const char*)&ldsv[0][0] + lr * 128 + ((64 + lg * 16) ^ rsw);
  const char* pr  = (const char*)&ldsp[wid][lr][lg * 8];

  f32x4 acc[4] = {};
  float lsum[4] = {0.f, 0.f, 0.f, 0.f};

  for (int t = 0; t < NTILE; ++t) {
    const int t0 = t * 64;
    __syncthreads();
    {
      const int chunk = wid;                    // 0..7 (1 KiB each), 1 pair/wave
      const int o = chunk * 1024 + lane * 16;
      const int r = o >> 7, cb = o & 127;       // 128 B per row
      const int scb = cb ^ ((r & 7) << 4);      // pre-swizzled source col
      gl_lds16((const char*)&k_ws[((size_t)bh * NKP + t0 + r) * HD] + scb,
               (char*)&ldsk[0][0] + chunk * 1024);
      gl_lds16((const char*)&vt_ws[((size_t)bh * HD + r) * NKP + t0] + scb,
               (char*)&ldsv[0][0] + chunk * 1024);
    }
    __syncthreads();

    // S = Q K^T (4 chunks of 16 keys)
    f32x4 s[4];
#pragma unroll
    for (int c = 0; c < 4; ++c) {
      bf16x8 kf0 = *(const bf16x8*)(kb0 + c * 2048);
      bf16x8 kf1 = *(const bf16x8*)(kb1 + c * 2048);
      f32x4 sa = {};
      __builtin_amdgcn_s_setprio(1);
      sa = __builtin_amdgcn_mfma_f32_16x16x32_bf16(qf[0], kf0, sa, 0, 0, 0);
      sa = __builtin_amdgcn_mfma_f32_16x16x32_bf16(qf[1], kf1, sa, 0, 0, 0);
      __builtin_amdgcn_s_setprio(0);
      s[c] = sa;
    }
    // p = exp(s*scale), TRUNCATED to bf16; l accumulates the truncated value
#pragma unroll
    for (int c = 0; c < 4; ++c)
#pragma unroll
      for (int r = 0; r < 4; ++r) {
        union { float f; uint32_t u; } pv;
        pv.f = __expf(s[c][r] * scale);
        ldsp[wid][lg * 4 + r][c * 16 + lr] = (uint16_t)(pv.u >> 16);
        pv.u &= 0xffff0000u;
        lsum[r] += pv.f;
      }
    // ordering fence: scalar u16 writes -> vector bf16x8 read, same wave
    asm volatile("" ::: "memory");
    __builtin_amdgcn_sched_barrier(0);
    // O += P V
    __builtin_amdgcn_s_setprio(1);
#pragma unroll
    for (int kk = 0; kk < 2; ++kk) {
      bf16x8 pf = *(const bf16x8*)(pr + kk * 64);
#pragma unroll
      for (int cd = 0; cd < 4; ++cd) {
        bf16x8 vf = *(const bf16x8*)((kk ? vb1 : vb0) + cd * 2048);
        acc[cd] = __builtin_amdgcn_mfma_f32_16x16x32_bf16(pf, vf, acc[cd], 0, 0, 0);
      }
    }
    __builtin_amdgcn_s_setprio(0);
  }
  // final l reduce (16-lane groups), drop the 63 phantom keys, normalize, write O
#pragma unroll
  for (int r = 0; r < 4; ++r) {
    float l = lsum[r];
    l += __shfl_xor(l, 1); l += __shfl_xor(l, 2);
    l += __shfl_xor(l, 4); l += __shfl_xor(l, 8);
    l -= 63.0f;
    const float inv = 1.0f / l;
    const int n = qrow0 + lg * 4 + r;
    size_t base = ((size_t)b * NN + n) * DIMF + h * HD;
#pragma unroll
    for (int cd = 0; cd < 4; ++cd)
      o_ws[base + cd * 16 + lr] = f2b(acc[cd][r] * inv);
  }
}

extern "C" void kernel_launch(void* const* d_in, const int* in_sizes, int n_in,
                              void* d_out, int out_size, void* d_ws, size_t ws_size,
                              hipStream_t stream) {
  const float* x      = (const float*)d_in[0];
  const float* wqkv   = (const float*)d_in[1];
  const float* wout   = (const float*)d_in[2];
  const float* bout   = (const float*)d_in[3];
  // d_in[4] = void_q: unused (void query row is dropped by the reference)
  const float* voidk  = (const float*)d_in[5];
  const float* voidv  = (const float*)d_in[6];
  const float* trace  = (const float*)d_in[7];
  const float* factor = (const float*)d_in[8];
  float* out = (float*)d_out;           // reference output dtype is FP32

  uint16_t* ws    = (uint16_t*)d_ws;
  uint16_t* x_bf  = ws;                       // 2*2048*1024  = 4,194,304 elems
  uint16_t* o_ws  = x_bf;                     // ALIAS: x_bf dead after gemm0
  uint16_t* wqkvT = x_bf  + 4194304;          // 3072*1024    = 3,145,728
  uint16_t* woutT = wqkvT + 3145728;          // 1024*1024    = 1,048,576
  uint16_t* q_ws  = woutT + 1048576;          // 2*16*2048*64 = 4,194,304
  uint16_t* k_ws  = q_ws  + 4194304;          // 2*16*2112*64 = 4,325,376
  uint16_t* vt_ws = k_ws  + 4325376;          // 4,325,376   (total ~42.5 MB)

  prep_k<<<dim3(8704), dim3(256), 0, stream>>>(x, x_bf, voidk, voidv, k_ws, vt_ws,
                                               wqkv, wqkvT, wout, woutT);
  gemm0_k<<<dim3(3072 / 128, 4096 / 128), dim3(256), 0, stream>>>(
      x_bf, wqkvT, 1024, q_ws, k_ws, vt_ws);
  attn_k<<<dim3(HEADS * BB, NN / 128), dim3(512), 0, stream>>>(
      q_ws, k_ws, vt_ws, trace, factor, o_ws);
  gemm1_k<<<dim3(1024 / 128, 4096 / 64), dim3(256), 0, stream>>>(
      o_ws, woutT, 1024, out, bout);
}